// Round 8
// baseline (282.137 us; speedup 1.0000x reference)
//
#include <hip/hip_runtime.h>
#include <math.h>

// B=4, C=64, H=W=64, N=4096, NPIX=16384. All fp32 in/out.
// Pixel-major [pix][ch] bf16 hi/lo pipeline. ws (floats), footprint 5M+256:
//  A ws+0..1M   : xT hi/lo -> x1T hi/lo -> O0 (attn partial fp32) -> c2T fp32
//  B ws+1M..2M  : c1T fp32 -> O1 (attn partial fp32)
//  C ws+2M..3M  : thT hi/lo -> zT hi/lo
//  D ws+3M..4M  : phT hi/lo
//  E ws+4M..4.5M: g16 (bf16 [B][C][N])
//  wp ws+4.5M   : prepped weights ; part/lp ws+5M-65536 ; stats ws+5M

typedef __attribute__((ext_vector_type(8))) short short8;
typedef __attribute__((ext_vector_type(4))) float f32x4;

__device__ __forceinline__ ushort f2bf(float x) {
    unsigned u = __float_as_uint(x);
    unsigned r = (u + 0x7FFFu + ((u >> 16) & 1u)) >> 16;  // RNE
    return (ushort)r;
}
__device__ __forceinline__ float bf2f(ushort h) {
    return __uint_as_float(((unsigned)h) << 16);
}

// ---------------------------------------------------------------------------
// prep_all: blocks <256: x -> xT [pix][ch] bf16 hi/lo. blocks >=256: weights.
// ---------------------------------------------------------------------------
__global__ __launch_bounds__(256) void prep_all_k(
    const float* __restrict__ x, ushort* __restrict__ xh,
    ushort* __restrict__ xl,
    const float* __restrict__ w0, const float* __restrict__ w1,
    const float* __restrict__ w2, const float* __restrict__ w3,
    const float* __restrict__ w4, const float* __restrict__ w5,
    ushort* __restrict__ wbase)
{
    __shared__ __align__(16) float T[64 * 68];
    const int blk = blockIdx.x, t = threadIdx.x;
    if (blk < 256) {
        const int b = blk >> 6, n0 = (blk & 63) << 6;
        for (int p = t; p < 1024; p += 256) {
            int c = p >> 4, n4 = (p & 15) << 2;
            *(float4*)&T[c * 68 + n4] =
                *(const float4*)&x[(((size_t)(b * 64 + c)) << 12) + n0 + n4];
        }
        __syncthreads();
        for (int p = t; p < 1024; p += 256) {
            int n = p >> 4, c4 = (p & 15) << 2;
            size_t off = (((size_t)(b * 4096 + n0 + n)) << 6) + c4;
            ushort4 hi, lo;
            float v;
            v = T[(c4 + 0) * 68 + n]; hi.x = f2bf(v); lo.x = f2bf(v - bf2f(hi.x));
            v = T[(c4 + 1) * 68 + n]; hi.y = f2bf(v); lo.y = f2bf(v - bf2f(hi.y));
            v = T[(c4 + 2) * 68 + n]; hi.z = f2bf(v); lo.z = f2bf(v - bf2f(hi.z));
            v = T[(c4 + 3) * 68 + n]; hi.w = f2bf(v); lo.w = f2bf(v - bf2f(hi.w));
            *(ushort4*)&xh[off] = hi;
            *(ushort4*)&xl[off] = lo;
        }
    } else {
        const float* W[6] = {w0, w1, w2, w3, w4, w5};
        int q = blk - 256;
        if (q < 720) {
            int s = q / 144, bi = q - s * 144;
            int idx = bi * 256 + t;
            if (idx >= 36864) return;
            int co = idx / 576;
            int r = idx - co * 576;
            int ci = r / 9;
            int tap = r - ci * 9;
            float v = W[s][idx];
            ushort* hi = wbase + (size_t)s * 73728;
            ushort* lo = hi + 36864;
            int off = tap * 4096 + co * 64 + ci;
            ushort h = f2bf(v);
            hi[off] = h;
            lo[off] = f2bf(v - bf2f(h));
        } else {
            int idx = (q - 720) * 256 + t;
            if (idx >= 4096) return;
            float v = W[5][idx];
            ushort* hi = wbase + 5 * 73728;
            ushort* lo = hi + 4096;
            ushort h = f2bf(v);
            hi[idx] = h;
            lo[idx] = f2bf(v - bf2f(h));
        }
    }
}

// ---------------------------------------------------------------------------
// MFMA 3x3 conv, r3 geometry (proven): block = 64 pix (one h-row) x 64 co,
// grid 256, wave tile 32pix x 32co. hi/lo compensated (3 MFMA/product).
// MODE 0: fp32 out [pix][co] + fused BN partial stats -> part[blk*64+ch].
// MODE 1 (NOUT=3): theta/phi -> hi/lo [pix][co]; g -> bf16 [B][co][n].
// ---------------------------------------------------------------------------
template <int NOUT, int MODE>
__global__ __launch_bounds__(256) void conv_mfma_k(
    const ushort* __restrict__ Ah, const ushort* __restrict__ Al,
    const ushort* __restrict__ w0h, const ushort* __restrict__ w0l,
    const ushort* __restrict__ w1h, const ushort* __restrict__ w1l,
    const ushort* __restrict__ w2h, const ushort* __restrict__ w2l,
    const float* __restrict__ b0, const float* __restrict__ b1,
    const float* __restrict__ b2,
    float* __restrict__ outF, float* __restrict__ part,
    ushort* __restrict__ o0h, ushort* __restrict__ o0l,
    ushort* __restrict__ o1h, ushort* __restrict__ o1l,
    ushort* __restrict__ o2t)
{
    __shared__ float redS[4][32], redSS[4][32];
    const int t = threadIdx.x, lane = t & 63, wv = t >> 6;
    const int quad = lane >> 4, l15 = lane & 15;
    const int blk = blockIdx.x;  // b*64 + h
    const int h = blk & 63;
    const int P0 = blk << 6;
    const int rhalf = (wv >> 1) << 5, chalf = (wv & 1) << 5;

    const ushort* wh[3] = {w0h, w1h, w2h};
    const ushort* wl[3] = {w0l, w1l, w2l};

    f32x4 acc[NOUT][2][2];
#pragma unroll
    for (int o = 0; o < NOUT; ++o)
#pragma unroll
        for (int rb = 0; rb < 2; ++rb)
#pragma unroll
            for (int cb = 0; cb < 2; ++cb)
#pragma unroll
                for (int j = 0; j < 4; ++j) acc[o][rb][cb][j] = 0.f;

#pragma unroll
    for (int dh = -1; dh <= 1; ++dh) {
        if ((unsigned)(h + dh) >= 64u) continue;  // block-uniform
#pragma unroll
        for (int dw = -1; dw <= 1; ++dw) {
            const int tap = (dh + 1) * 3 + (dw + 1);
#pragma unroll
            for (int kc = 0; kc < 2; ++kc) {
                const int k0 = kc * 32 + quad * 8;
                short8 aH[2], aL[2];
#pragma unroll
                for (int rb = 0; rb < 2; ++rb) {
                    int wrow = rhalf + (rb << 4) + l15;
                    int sw = wrow + dw;
                    short8 z = {0, 0, 0, 0, 0, 0, 0, 0};
                    aH[rb] = z;
                    aL[rb] = z;
                    if ((unsigned)sw < 64u) {
                        int sp = P0 + dh * 64 + sw;
                        size_t off = (((size_t)sp) << 6) + k0;
                        aH[rb] = *(const short8*)&Ah[off];
                        aL[rb] = *(const short8*)&Al[off];
                    }
                }
#pragma unroll
                for (int o = 0; o < NOUT; ++o) {
#pragma unroll
                    for (int cb = 0; cb < 2; ++cb) {
                        int co = chalf + (cb << 4) + l15;
                        size_t woff = (((size_t)tap) << 12) + (((size_t)co) << 6) + k0;
                        short8 bH = *(const short8*)&wh[o][woff];
                        short8 bL = *(const short8*)&wl[o][woff];
#pragma unroll
                        for (int rb = 0; rb < 2; ++rb) {
                            acc[o][rb][cb] = __builtin_amdgcn_mfma_f32_16x16x32_bf16(
                                aH[rb], bH, acc[o][rb][cb], 0, 0, 0);
                            acc[o][rb][cb] = __builtin_amdgcn_mfma_f32_16x16x32_bf16(
                                aH[rb], bL, acc[o][rb][cb], 0, 0, 0);
                            acc[o][rb][cb] = __builtin_amdgcn_mfma_f32_16x16x32_bf16(
                                aL[rb], bH, acc[o][rb][cb], 0, 0, 0);
                        }
                    }
                }
            }
        }
    }

    if (MODE == 0) {
        float s_[2], ss_[2];
#pragma unroll
        for (int cb = 0; cb < 2; ++cb) {
            int co = chalf + (cb << 4) + l15;
            float s = 0.f, ss = 0.f;
#pragma unroll
            for (int rb = 0; rb < 2; ++rb)
#pragma unroll
                for (int r = 0; r < 4; ++r) {
                    int pix = P0 + rhalf + (rb << 4) + (quad << 2) + r;
                    float v = acc[0][rb][cb][r];
                    outF[(((size_t)pix) << 6) + co] = v;
                    s += v;
                    ss += v * v;
                }
            s_[cb] = s;
            ss_[cb] = ss;
        }
#pragma unroll
        for (int off = 16; off < 64; off <<= 1) {
#pragma unroll
            for (int cb = 0; cb < 2; ++cb) {
                s_[cb] += __shfl_xor(s_[cb], off);
                ss_[cb] += __shfl_xor(ss_[cb], off);
            }
        }
        if (quad == 0) {
#pragma unroll
            for (int cb = 0; cb < 2; ++cb) {
                redS[wv][(cb << 4) + l15] = s_[cb];
                redSS[wv][(cb << 4) + l15] = ss_[cb];
            }
        }
        __syncthreads();
        if (t < 64) {
            int w01 = (t >> 5) & 1;  // chalf bit
            float S = redS[w01][t & 31] + redS[w01 + 2][t & 31];
            float SS = redSS[w01][t & 31] + redSS[w01 + 2][t & 31];
            part[blk * 64 + t] = S;
            part[16384 + blk * 64 + t] = SS;
        }
    } else {
        const int b = P0 >> 12;
#pragma unroll
        for (int rb = 0; rb < 2; ++rb)
#pragma unroll
            for (int cb = 0; cb < 2; ++cb) {
                int co = chalf + (cb << 4) + l15;
                float bth = b0[co], bph = b1[co], bg = b2[co];
                int pixb = P0 + rhalf + (rb << 4) + (quad << 2);
#pragma unroll
                for (int r = 0; r < 4; ++r) {
                    size_t off = (((size_t)(pixb + r)) << 6) + co;
                    float v = acc[0][rb][cb][r] + bth;
                    ushort hh = f2bf(v);
                    o0h[off] = hh;
                    o0l[off] = f2bf(v - bf2f(hh));
                    v = acc[1][rb][cb][r] + bph;
                    hh = f2bf(v);
                    o1h[off] = hh;
                    o1l[off] = f2bf(v - bf2f(hh));
                }
                int n0 = pixb & 4095;
                ushort4 gv;
                gv.x = f2bf(acc[2][rb][cb][0] + bg);
                gv.y = f2bf(acc[2][rb][cb][1] + bg);
                gv.z = f2bf(acc[2][rb][cb][2] + bg);
                gv.w = f2bf(acc[2][rb][cb][3] + bg);
                *(ushort4*)&o2t[(((size_t)b) << 18) + (((size_t)co) << 12) + n0] = gv;
            }
    }
}

// ---------------------------------------------------------------------------
// statsB: reduce 256 block-partials per channel -> BN scale/shift.
// ---------------------------------------------------------------------------
__global__ __launch_bounds__(256) void statsB_k(
    const float* __restrict__ part, const float* __restrict__ gamma,
    const float* __restrict__ beta, float* __restrict__ scale,
    float* __restrict__ shift)
{
    __shared__ float rs[4][64], rss[4][64];
    const int t = threadIdx.x, c = t & 63, seg = t >> 6;
    float S = 0.f, SS = 0.f;
    for (int k = seg * 64; k < seg * 64 + 64; ++k) {
        S += part[k * 64 + c];
        SS += part[16384 + k * 64 + c];
    }
    rs[seg][c] = S;
    rss[seg][c] = SS;
    __syncthreads();
    if (t < 64) {
        float Sf = rs[0][t] + rs[1][t] + rs[2][t] + rs[3][t];
        float SSf = rss[0][t] + rss[1][t] + rss[2][t] + rss[3][t];
        float mean = Sf * (1.f / 16384.f);
        float var = SSf * (1.f / 16384.f) - mean * mean;
        float sc = gamma[t] * rsqrtf(var + 1e-5f);
        scale[t] = sc;
        shift[t] = beta[t] - mean * sc;
    }
}

// ---------------------------------------------------------------------------
// x1prep: c1T fp32 [pix][ch] -> relu(BN) -> x1T bf16 hi/lo.
// ---------------------------------------------------------------------------
__global__ __launch_bounds__(256) void x1prep_k(
    const float* __restrict__ c1T, const float* __restrict__ sc,
    const float* __restrict__ sh, ushort* __restrict__ xh,
    ushort* __restrict__ xl)
{
    int p = blockIdx.x * 256 + threadIdx.x;  // < 262144
    int c4 = (p & 15) << 2;
    float4 v = *(const float4*)&c1T[(size_t)p << 2];
    float4 s4 = *(const float4*)&sc[c4];
    float4 h4 = *(const float4*)&sh[c4];
    float r0 = fmaxf(v.x * s4.x + h4.x, 0.f);
    float r1 = fmaxf(v.y * s4.y + h4.y, 0.f);
    float r2 = fmaxf(v.z * s4.z + h4.z, 0.f);
    float r3 = fmaxf(v.w * s4.w + h4.w, 0.f);
    ushort4 hi, lo;
    hi.x = f2bf(r0); lo.x = f2bf(r0 - bf2f(hi.x));
    hi.y = f2bf(r1); lo.y = f2bf(r1 - bf2f(hi.y));
    hi.z = f2bf(r2); lo.z = f2bf(r2 - bf2f(hi.z));
    hi.w = f2bf(r3); lo.w = f2bf(r3 - bf2f(hi.w));
    *(ushort4*)&xh[(size_t)p << 2] = hi;
    *(ushort4*)&xl[(size_t)p << 2] = lo;
}

// ---------------------------------------------------------------------------
// Flash attention v8: NO K/V LDS at all. K and V fragments are loaded
// DIRECTLY from global (coalesced 64B-per-row patterns, per-XCD L2-resident
// thanks to the XCD swizzle) with explicit one-step REGISTER double-buffer
// (r4's failure was un-prefetched + L2-thrashing; both fixed here).
// K-lo term dropped: S = (Qhi+Qlo)·Khi (error ~3e-3 in logits, negligible).
// Only P round-trips LDS (C->A layout transform), double-buffered ->
// ONE barrier/step, LDS = 16 KB. Static max M=30; partial O/l out (2-way
// KV split as r5-r7).
// ---------------------------------------------------------------------------
__device__ __forceinline__ short8 ldfrag(const ushort* base, int row, int ch) {
    return *(const short8*)&base[(row << 6) + (((ch ^ (row & 7))) << 3)];
}

__global__ __launch_bounds__(256, 2) void attn_k(
    const ushort* __restrict__ thT_hi, const ushort* __restrict__ thT_lo,
    const ushort* __restrict__ phT_hi, const ushort* __restrict__ phT_lo,
    const ushort* __restrict__ g16, float* __restrict__ O0,
    float* __restrict__ O1, float* __restrict__ lp)
{
    __shared__ __align__(16) ushort Pt[2][4096];

    const int t = threadIdx.x;
    const int bx = blockIdx.x;
    const int xslot = bx & 7;
    const int b = xslot & 3;
    const int half = xslot >> 2;
    const int q0 = (bx >> 3) << 6;
    const int mbase = half << 11;
    const int lane = t & 63;
    const int wv = t >> 6;
    const int quad = lane >> 4;
    const int l15 = lane & 15;
    const int rhalf = (wv >> 1) << 5;   // q-half
    const int chalf = (wv & 1) << 5;    // m-half (S) / c-half (PV)

    const size_t cb64 = ((size_t)b) << 18;
    const ushort* Qh_g = thT_hi + cb64 + (((size_t)q0) << 6);
    const ushort* Ql_g = thT_lo + cb64 + (((size_t)q0) << 6);
    const ushort* Kh_g = phT_hi + cb64;
    const ushort* Vg = g16 + cb64;
    float* Op = half ? O1 : O0;
    float* lpd = lp + (half << 14);
    (void)phT_lo;

    // hoisted Q A-frags (step-invariant)
    short8 aHi[2][2], aLo[2][2];
#pragma unroll
    for (int rb = 0; rb < 2; ++rb)
#pragma unroll
        for (int ks = 0; ks < 2; ++ks) {
            size_t off = (((size_t)(rhalf + (rb << 4) + l15)) << 6) +
                         ks * 32 + quad * 8;
            aHi[rb][ks] = *(const short8*)&Qh_g[off];
            aLo[rb][ks] = *(const short8*)&Ql_g[off];
        }

    // K/V fragment global addresses (per cb,ks), step advances by +64 in m
    // K B-frag: rows m = m0+chalf+cb*16+l15, k = ch: ks*32+quad*8
    // V B-frag: rows c = chalf+cb*16+l15,   k = m:  m0+ks*32+quad*8
    short8 kf[2][2], vf[2][2];
#pragma unroll
    for (int cb = 0; cb < 2; ++cb)
#pragma unroll
        for (int ks = 0; ks < 2; ++ks) {
            int kv = mbase + chalf + (cb << 4) + l15;
            kf[cb][ks] = *(const short8*)&Kh_g[(((size_t)kv) << 6) +
                                               ks * 32 + quad * 8];
            int c = chalf + (cb << 4) + l15;
            vf[cb][ks] = *(const short8*)&Vg[(((size_t)c) << 12) + mbase +
                                             ks * 32 + quad * 8];
        }

    f32x4 oacc[2][2];
    f32x4 lacc[2];
#pragma unroll
    for (int rb = 0; rb < 2; ++rb) {
#pragma unroll
        for (int j = 0; j < 4; ++j) lacc[rb][j] = 0.f;
#pragma unroll
        for (int cb = 0; cb < 2; ++cb)
#pragma unroll
            for (int j = 0; j < 4; ++j) oacc[rb][cb][j] = 0.f;
    }
    short8 onesB;
    {
        short ov = (l15 == 0) ? (short)0x3F80 : (short)0;
#pragma unroll
        for (int j = 0; j < 8; ++j) onesB[j] = ov;
    }

    for (int step = 0; step < 32; ++step) {
        const int buf = step & 1;

        // register prefetch of next step's K/V frags (consumed next iter)
        short8 nkf[2][2], nvf[2][2];
        if (step < 31) {
            const int m1 = mbase + ((step + 1) << 6);
#pragma unroll
            for (int cb = 0; cb < 2; ++cb)
#pragma unroll
                for (int ks = 0; ks < 2; ++ks) {
                    int kv = m1 + chalf + (cb << 4) + l15;
                    nkf[cb][ks] = *(const short8*)&Kh_g[(((size_t)kv) << 6) +
                                                        ks * 32 + quad * 8];
                    int c = chalf + (cb << 4) + l15;
                    nvf[cb][ks] = *(const short8*)&Vg[(((size_t)c) << 12) + m1 +
                                                      ks * 32 + quad * 8];
                }
        }

        // ---- S = (Qhi+Qlo) x K^T
        f32x4 sacc[2][2];
#pragma unroll
        for (int rb = 0; rb < 2; ++rb)
#pragma unroll
            for (int cb = 0; cb < 2; ++cb)
#pragma unroll
                for (int j = 0; j < 4; ++j) sacc[rb][cb][j] = 0.f;
#pragma unroll
        for (int ks = 0; ks < 2; ++ks)
#pragma unroll
            for (int rb = 0; rb < 2; ++rb)
#pragma unroll
                for (int cb = 0; cb < 2; ++cb) {
                    sacc[rb][cb] = __builtin_amdgcn_mfma_f32_16x16x32_bf16(
                        aHi[rb][ks], kf[cb][ks], sacc[rb][cb], 0, 0, 0);
                    sacc[rb][cb] = __builtin_amdgcn_mfma_f32_16x16x32_bf16(
                        aLo[rb][ks], kf[cb][ks], sacc[rb][cb], 0, 0, 0);
                }

        // ---- exp, P -> LDS (bf16, XOR swizzle), double-buffered
#pragma unroll
        for (int rb = 0; rb < 2; ++rb)
#pragma unroll
            for (int cb = 0; cb < 2; ++cb) {
                int pcol = chalf + (cb << 4) + l15;
#pragma unroll
                for (int r = 0; r < 4; ++r) {
                    int prow = rhalf + (rb << 4) + (quad << 2) + r;
                    float p = __expf(sacc[rb][cb][r] - 30.f);
                    Pt[buf][(prow << 6) + (((pcol >> 3) ^ (prow & 7)) << 3) +
                            (pcol & 7)] = f2bf(p);
                }
            }
        __syncthreads();  // the ONLY barrier per step

        // ---- O += P V, l += P·1  (V from registers)
        short8 pa[2][2];
#pragma unroll
        for (int rb = 0; rb < 2; ++rb) {
            int row = rhalf + (rb << 4) + l15;
#pragma unroll
            for (int ks = 0; ks < 2; ++ks)
                pa[rb][ks] = ldfrag(&Pt[buf][0], row, (ks << 2) + quad);
        }
#pragma unroll
        for (int ks = 0; ks < 2; ++ks)
#pragma unroll
            for (int rb = 0; rb < 2; ++rb)
#pragma unroll
                for (int cb = 0; cb < 2; ++cb)
                    oacc[rb][cb] = __builtin_amdgcn_mfma_f32_16x16x32_bf16(
                        pa[rb][ks], vf[cb][ks], oacc[rb][cb], 0, 0, 0);
#pragma unroll
        for (int rb = 0; rb < 2; ++rb)
#pragma unroll
            for (int ks = 0; ks < 2; ++ks)
                lacc[rb] = __builtin_amdgcn_mfma_f32_16x16x32_bf16(
                    pa[rb][ks], onesB, lacc[rb], 0, 0, 0);

        // rotate register double-buffer
        if (step < 31) {
#pragma unroll
            for (int cb = 0; cb < 2; ++cb)
#pragma unroll
                for (int ks = 0; ks < 2; ++ks) {
                    kf[cb][ks] = nkf[cb][ks];
                    vf[cb][ks] = nvf[cb][ks];
                }
        }
    }

    // epilogue: write partial l (col-0 lanes) and partial O (no division)
#pragma unroll
    for (int rb = 0; rb < 2; ++rb) {
        if ((wv & 1) == 0 && l15 == 0) {
#pragma unroll
            for (int r = 0; r < 4; ++r) {
                int nn = q0 + rhalf + (rb << 4) + (quad << 2) + r;
                lpd[(b << 12) + nn] = lacc[rb][r];
            }
        }
#pragma unroll
        for (int cb = 0; cb < 2; ++cb) {
            int cc = chalf + (cb << 4) + l15;
#pragma unroll
            for (int r = 0; r < 4; ++r) {
                int nn = q0 + rhalf + (rb << 4) + (quad << 2) + r;
                Op[cb64 + (((size_t)nn) << 6) + cc] = oacc[rb][cb][r];
            }
        }
    }
}

// ---------------------------------------------------------------------------
// 1x1 conv + bias + residual, MFMA, with FUSED attention reduce:
// y = (O0+O1)/(l0+l1) built in-register as bf16 hi/lo A-frags.
// ---------------------------------------------------------------------------
__global__ __launch_bounds__(256) void conv1x1_k(
    const float* __restrict__ O0, const float* __restrict__ O1,
    const float* __restrict__ lp,
    const ushort* __restrict__ wh, const ushort* __restrict__ wl,
    const float* __restrict__ Wb, const float* __restrict__ x,
    ushort* __restrict__ zh, ushort* __restrict__ zl)
{
    const int t = threadIdx.x, lane = t & 63, wv = t >> 6;
    const int quad = lane >> 4, l15 = lane & 15;
    const int chalf = (wv & 1) << 5;
    const int P0 = blockIdx.x << 5;
    const int pbase = P0 + ((wv >> 1) << 4);
    const int b = P0 >> 12;
    const int pix = pbase + l15;   // A row
    const int nn = pix & 4095;
    const float linv = 1.f / (lp[(b << 12) + nn] + lp[16384 + (b << 12) + nn]);

    f32x4 acc[2];
#pragma unroll
    for (int j = 0; j < 4; ++j) { acc[0][j] = 0.f; acc[1][j] = 0.f; }

#pragma unroll
    for (int kc = 0; kc < 2; ++kc) {
        const int k0 = kc * 32 + quad * 8;
        size_t ao = (((size_t)pix) << 6) + k0;
        float4 a0 = *(const float4*)&O0[ao];
        float4 a1 = *(const float4*)&O0[ao + 4];
        float4 c0 = *(const float4*)&O1[ao];
        float4 c1 = *(const float4*)&O1[ao + 4];
        float v[8] = {(a0.x + c0.x) * linv, (a0.y + c0.y) * linv,
                      (a0.z + c0.z) * linv, (a0.w + c0.w) * linv,
                      (a1.x + c1.x) * linv, (a1.y + c1.y) * linv,
                      (a1.z + c1.z) * linv, (a1.w + c1.w) * linv};
        short8 aH, aL;
#pragma unroll
        for (int j = 0; j < 8; ++j) {
            ushort hh = f2bf(v[j]);
            aH[j] = (short)hh;
            aL[j] = (short)f2bf(v[j] - bf2f(hh));
        }
#pragma unroll
        for (int cb = 0; cb < 2; ++cb) {
            int co = chalf + (cb << 4) + l15;
            short8 bH = *(const short8*)&wh[(((size_t)co) << 6) + k0];
            short8 bL = *(const short8*)&wl[(((size_t)co) << 6) + k0];
            acc[cb] = __builtin_amdgcn_mfma_f32_16x16x32_bf16(aH, bH, acc[cb], 0, 0, 0);
            acc[cb] = __builtin_amdgcn_mfma_f32_16x16x32_bf16(aH, bL, acc[cb], 0, 0, 0);
            acc[cb] = __builtin_amdgcn_mfma_f32_16x16x32_bf16(aL, bH, acc[cb], 0, 0, 0);
        }
    }

    const int pixb = pbase + (quad << 2);
    const int n0 = pixb & 4095;
#pragma unroll
    for (int cb = 0; cb < 2; ++cb) {
        int co = chalf + (cb << 4) + l15;
        float bias = Wb[co];
        float4 xr = *(const float4*)&x[(((size_t)(b * 64 + co)) << 12) + n0];
        float xa[4] = {xr.x, xr.y, xr.z, xr.w};
#pragma unroll
        for (int r = 0; r < 4; ++r) {
            float v = acc[cb][r] + bias + xa[r];
            size_t off = (((size_t)(pixb + r)) << 6) + co;
            ushort hh = f2bf(v);
            zh[off] = hh;
            zl[off] = f2bf(v - bf2f(hh));
        }
    }
}

// ---------------------------------------------------------------------------
// Final: BN2 apply + relu + transpose back to [B][C][H][W].
// ---------------------------------------------------------------------------
__global__ __launch_bounds__(256) void bnreluT_k(
    const float* __restrict__ c2T, const float* __restrict__ sc,
    const float* __restrict__ sh, float* __restrict__ out)
{
    __shared__ __align__(16) float T[64 * 68];
    const int b = blockIdx.x >> 6, n0 = (blockIdx.x & 63) << 6, t = threadIdx.x;
    for (int p = t; p < 1024; p += 256) {
        int n = p >> 4, c4 = (p & 15) << 2;
        float4 v = *(const float4*)&c2T[(((size_t)(b * 4096 + n0 + n)) << 6) + c4];
        float4 s4 = *(const float4*)&sc[c4];
        float4 h4 = *(const float4*)&sh[c4];
        T[(c4 + 0) * 68 + n] = fmaxf(v.x * s4.x + h4.x, 0.f);
        T[(c4 + 1) * 68 + n] = fmaxf(v.y * s4.y + h4.y, 0.f);
        T[(c4 + 2) * 68 + n] = fmaxf(v.z * s4.z + h4.z, 0.f);
        T[(c4 + 3) * 68 + n] = fmaxf(v.w * s4.w + h4.w, 0.f);
    }
    __syncthreads();
    for (int p = t; p < 1024; p += 256) {
        int c = p >> 4, n4 = (p & 15) << 2;
        float4 r;
        r.x = T[c * 68 + n4 + 0];
        r.y = T[c * 68 + n4 + 1];
        r.z = T[c * 68 + n4 + 2];
        r.w = T[c * 68 + n4 + 3];
        *(float4*)&out[(((size_t)(b * 64 + c)) << 12) + n0 + n4] = r;
    }
}

// ---------------------------------------------------------------------------
extern "C" void kernel_launch(void* const* d_in, const int* in_sizes, int n_in,
                              void* d_out, int out_size, void* d_ws,
                              size_t ws_size, hipStream_t stream)
{
    const float* x    = (const float*)d_in[0];
    const float* c1w  = (const float*)d_in[1];
    const float* bn1g = (const float*)d_in[2];
    const float* bn1b = (const float*)d_in[3];
    const float* thw  = (const float*)d_in[4];
    const float* thb  = (const float*)d_in[5];
    const float* phw  = (const float*)d_in[6];
    const float* phb  = (const float*)d_in[7];
    const float* gw   = (const float*)d_in[8];
    const float* gb   = (const float*)d_in[9];
    const float* Wwt  = (const float*)d_in[10];
    const float* Wbs  = (const float*)d_in[11];
    const float* c2w  = (const float*)d_in[12];
    const float* bn2g = (const float*)d_in[13];
    const float* bn2b = (const float*)d_in[14];
    float* out = (float*)d_out;

    float* ws = (float*)d_ws;
    // region A: xT/x1T hi+lo -> O0 fp32 -> c2T fp32
    ushort* xT_hi = (ushort*)ws;
    ushort* xT_lo = xT_hi + (1 << 20);
    ushort* x1T_hi = xT_hi;
    ushort* x1T_lo = xT_lo;
    float* O0 = ws;
    float* c2T = ws;
    // region B: c1T fp32 -> O1 fp32
    float* c1T = ws + (1 << 20);
    float* O1 = c1T;
    // region C: thT hi/lo -> zT hi/lo
    ushort* thT_hi = (ushort*)(ws + (2 << 20));
    ushort* thT_lo = thT_hi + (1 << 20);
    ushort* zT_hi = thT_hi;
    ushort* zT_lo = thT_lo;
    // regions D/E
    ushort* phT_hi = (ushort*)(ws + (3 << 20));
    ushort* phT_lo = phT_hi + (1 << 20);
    ushort* g16 = (ushort*)(ws + (4 << 20));
    // weights / partials / stats
    ushort* wp = (ushort*)(ws + (9 << 19));
    float* part = ws + (5 << 20) - 65536;  // also lp for attention
    float* stats = ws + (5 << 20);
    float* sc1 = stats, *sh1 = stats + 64, *sc2 = stats + 128, *sh2 = stats + 192;

    ushort* wc1h = wp;                ushort* wc1l = wc1h + 36864;
    ushort* wthh = wp + 1 * 73728;    ushort* wthl = wthh + 36864;
    ushort* wphh = wp + 2 * 73728;    ushort* wphl = wphh + 36864;
    ushort* wgh  = wp + 3 * 73728;    ushort* wgl  = wgh + 36864;
    ushort* wc2h = wp + 4 * 73728;    ushort* wc2l = wc2h + 36864;
    ushort* w11h = wp + 5 * 73728;    ushort* w11l = w11h + 4096;

    prep_all_k<<<992, 256, 0, stream>>>(x, xT_hi, xT_lo, c1w, thw, phw, gw,
                                        c2w, Wwt, wp);
    conv_mfma_k<1, 0><<<256, 256, 0, stream>>>(
        xT_hi, xT_lo, wc1h, wc1l, nullptr, nullptr, nullptr, nullptr,
        nullptr, nullptr, nullptr, c1T, part, nullptr, nullptr, nullptr,
        nullptr, nullptr);
    statsB_k<<<1, 256, 0, stream>>>(part, bn1g, bn1b, sc1, sh1);
    x1prep_k<<<1024, 256, 0, stream>>>(c1T, sc1, sh1, x1T_hi, x1T_lo);
    conv_mfma_k<3, 1><<<256, 256, 0, stream>>>(
        x1T_hi, x1T_lo, wthh, wthl, wphh, wphl, wgh, wgl, thb, phb, gb,
        nullptr, nullptr, thT_hi, thT_lo, phT_hi, phT_lo, g16);
    attn_k<<<512, 256, 0, stream>>>(thT_hi, thT_lo, phT_hi, phT_lo, g16,
                                    O0, O1, part);
    conv1x1_k<<<512, 256, 0, stream>>>(O0, O1, part, w11h, w11l, Wbs, x,
                                       zT_hi, zT_lo);
    conv_mfma_k<1, 0><<<256, 256, 0, stream>>>(
        zT_hi, zT_lo, wc2h, wc2l, nullptr, nullptr, nullptr, nullptr,
        nullptr, nullptr, nullptr, c2T, part, nullptr, nullptr, nullptr,
        nullptr, nullptr);
    statsB_k<<<1, 256, 0, stream>>>(part, bn2g, bn2b, sc2, sh2);
    bnreluT_k<<<256, 256, 0, stream>>>(c2T, sc2, sh2, out);
}

// Round 9
// 237.564 us; speedup vs baseline: 1.1876x; 1.1876x over previous
//
#include <hip/hip_runtime.h>
#include <math.h>

// B=4, C=64, H=W=64, N=4096, NPIX=16384. All fp32 in/out.
// Pixel-major [pix][ch] bf16 hi/lo pipeline. ws (floats), footprint 5M+256:
//  A ws+0..1M   : xT hi/lo -> x1T hi/lo -> O0 (attn partial fp32) -> c2T fp32
//  B ws+1M..2M  : c1T fp32 -> O1 (attn partial fp32)
//  C ws+2M..3M  : thT hi/lo -> zT hi/lo
//  D ws+3M..4M  : phT hi/lo
//  E ws+4M..4.5M: g16 (bf16 [B][C][N])
//  wp ws+4.5M   : prepped weights ; part/lp ws+5M-65536 ; stats ws+5M

typedef __attribute__((ext_vector_type(8))) short short8;
typedef __attribute__((ext_vector_type(4))) float f32x4;

__device__ __forceinline__ ushort f2bf(float x) {
    unsigned u = __float_as_uint(x);
    unsigned r = (u + 0x7FFFu + ((u >> 16) & 1u)) >> 16;  // RNE
    return (ushort)r;
}
__device__ __forceinline__ float bf2f(ushort h) {
    return __uint_as_float(((unsigned)h) << 16);
}

// ---------------------------------------------------------------------------
// prep_all: blocks <256: x -> xT [pix][ch] bf16 hi/lo. blocks >=256: weights.
// ---------------------------------------------------------------------------
__global__ __launch_bounds__(256) void prep_all_k(
    const float* __restrict__ x, ushort* __restrict__ xh,
    ushort* __restrict__ xl,
    const float* __restrict__ w0, const float* __restrict__ w1,
    const float* __restrict__ w2, const float* __restrict__ w3,
    const float* __restrict__ w4, const float* __restrict__ w5,
    ushort* __restrict__ wbase)
{
    __shared__ __align__(16) float T[64 * 68];
    const int blk = blockIdx.x, t = threadIdx.x;
    if (blk < 256) {
        const int b = blk >> 6, n0 = (blk & 63) << 6;
        for (int p = t; p < 1024; p += 256) {
            int c = p >> 4, n4 = (p & 15) << 2;
            *(float4*)&T[c * 68 + n4] =
                *(const float4*)&x[(((size_t)(b * 64 + c)) << 12) + n0 + n4];
        }
        __syncthreads();
        for (int p = t; p < 1024; p += 256) {
            int n = p >> 4, c4 = (p & 15) << 2;
            size_t off = (((size_t)(b * 4096 + n0 + n)) << 6) + c4;
            ushort4 hi, lo;
            float v;
            v = T[(c4 + 0) * 68 + n]; hi.x = f2bf(v); lo.x = f2bf(v - bf2f(hi.x));
            v = T[(c4 + 1) * 68 + n]; hi.y = f2bf(v); lo.y = f2bf(v - bf2f(hi.y));
            v = T[(c4 + 2) * 68 + n]; hi.z = f2bf(v); lo.z = f2bf(v - bf2f(hi.z));
            v = T[(c4 + 3) * 68 + n]; hi.w = f2bf(v); lo.w = f2bf(v - bf2f(hi.w));
            *(ushort4*)&xh[off] = hi;
            *(ushort4*)&xl[off] = lo;
        }
    } else {
        const float* W[6] = {w0, w1, w2, w3, w4, w5};
        int q = blk - 256;
        if (q < 720) {
            int s = q / 144, bi = q - s * 144;
            int idx = bi * 256 + t;
            if (idx >= 36864) return;
            int co = idx / 576;
            int r = idx - co * 576;
            int ci = r / 9;
            int tap = r - ci * 9;
            float v = W[s][idx];
            ushort* hi = wbase + (size_t)s * 73728;
            ushort* lo = hi + 36864;
            int off = tap * 4096 + co * 64 + ci;
            ushort h = f2bf(v);
            hi[off] = h;
            lo[off] = f2bf(v - bf2f(h));
        } else {
            int idx = (q - 720) * 256 + t;
            if (idx >= 4096) return;
            float v = W[5][idx];
            ushort* hi = wbase + 5 * 73728;
            ushort* lo = hi + 4096;
            ushort h = f2bf(v);
            hi[idx] = h;
            lo[idx] = f2bf(v - bf2f(h));
        }
    }
}

// ---------------------------------------------------------------------------
// MFMA 3x3 conv. Block = 32 pix x 64 co, grid 512 (2 blk/CU). Wave tile
// 16pix x 32co. A hi/lo compensated; W hi ONLY (2 MFMA/product — 0.2% rel
// weight error, BN-normalized downstream). Per-pixel load volume identical
// to the r3/r7 geometry; MFMA/pixel -33%; occupancy 2x.
// MODE 0: fp32 out [pix][co] + fused BN partial stats -> part[bx*64+ch].
// MODE 1 (NOUT=3): theta/phi -> hi/lo [pix][co]; g -> bf16 [B][co][n].
// ---------------------------------------------------------------------------
template <int NOUT, int MODE>
__global__ __launch_bounds__(256) void conv_mfma_k(
    const ushort* __restrict__ Ah, const ushort* __restrict__ Al,
    const ushort* __restrict__ w0h, const ushort* __restrict__ w1h,
    const ushort* __restrict__ w2h,
    const float* __restrict__ b0, const float* __restrict__ b1,
    const float* __restrict__ b2,
    float* __restrict__ outF, float* __restrict__ part,
    ushort* __restrict__ o0h, ushort* __restrict__ o0l,
    ushort* __restrict__ o1h, ushort* __restrict__ o1l,
    ushort* __restrict__ o2t)
{
    __shared__ float redS[4][32], redSS[4][32];
    const int t = threadIdx.x, lane = t & 63, wv = t >> 6;
    const int quad = lane >> 4, l15 = lane & 15;
    const int bx = blockIdx.x;
    const int row = bx >> 1;                            // b*64 + h
    const int h = row & 63;
    const int wb0 = ((bx & 1) << 5) + ((wv >> 1) << 4); // wave pixel base (w)
    const int chalf = (wv & 1) << 5;

    const ushort* wh[3] = {w0h, w1h, w2h};

    f32x4 acc[NOUT][2];
#pragma unroll
    for (int o = 0; o < NOUT; ++o)
#pragma unroll
        for (int cb = 0; cb < 2; ++cb)
#pragma unroll
            for (int j = 0; j < 4; ++j) acc[o][cb][j] = 0.f;

#pragma unroll
    for (int dh = -1; dh <= 1; ++dh) {
        if ((unsigned)(h + dh) >= 64u) continue;  // block-uniform
#pragma unroll
        for (int dw = -1; dw <= 1; ++dw) {
            const int tap = (dh + 1) * 3 + (dw + 1);
#pragma unroll
            for (int kc = 0; kc < 2; ++kc) {
                const int k0 = kc * 32 + quad * 8;
                const int sw = wb0 + l15 + dw;
                short8 aH = {0, 0, 0, 0, 0, 0, 0, 0};
                short8 aL = {0, 0, 0, 0, 0, 0, 0, 0};
                if ((unsigned)sw < 64u) {
                    size_t off = (((size_t)(((row + dh) << 6) + sw)) << 6) + k0;
                    aH = *(const short8*)&Ah[off];
                    aL = *(const short8*)&Al[off];
                }
#pragma unroll
                for (int o = 0; o < NOUT; ++o)
#pragma unroll
                    for (int cb = 0; cb < 2; ++cb) {
                        int co = chalf + (cb << 4) + l15;
                        short8 bH = *(const short8*)
                            &wh[o][(((size_t)tap) << 12) + (((size_t)co) << 6) + k0];
                        acc[o][cb] = __builtin_amdgcn_mfma_f32_16x16x32_bf16(
                            aH, bH, acc[o][cb], 0, 0, 0);
                        acc[o][cb] = __builtin_amdgcn_mfma_f32_16x16x32_bf16(
                            aL, bH, acc[o][cb], 0, 0, 0);
                    }
            }
        }
    }

    if (MODE == 0) {
        float s_[2], ss_[2];
#pragma unroll
        for (int cb = 0; cb < 2; ++cb) {
            int co = chalf + (cb << 4) + l15;
            float s = 0.f, ss = 0.f;
#pragma unroll
            for (int r = 0; r < 4; ++r) {
                int pix = (row << 6) + wb0 + (quad << 2) + r;
                float v = acc[0][cb][r];
                outF[(((size_t)pix) << 6) + co] = v;
                s += v;
                ss += v * v;
            }
            s_[cb] = s;
            ss_[cb] = ss;
        }
#pragma unroll
        for (int off = 16; off < 64; off <<= 1) {
#pragma unroll
            for (int cb = 0; cb < 2; ++cb) {
                s_[cb] += __shfl_xor(s_[cb], off);
                ss_[cb] += __shfl_xor(ss_[cb], off);
            }
        }
        if (quad == 0) {
#pragma unroll
            for (int cb = 0; cb < 2; ++cb) {
                redS[wv][(cb << 4) + l15] = s_[cb];
                redSS[wv][(cb << 4) + l15] = ss_[cb];
            }
        }
        __syncthreads();
        if (t < 64) {
            int w01 = (t >> 5) & 1;  // chalf bit
            float S = redS[w01][t & 31] + redS[w01 + 2][t & 31];
            float SS = redSS[w01][t & 31] + redSS[w01 + 2][t & 31];
            part[bx * 64 + t] = S;
            part[32768 + bx * 64 + t] = SS;
        }
    } else {
        const int b = row >> 6;
#pragma unroll
        for (int cb = 0; cb < 2; ++cb) {
            int co = chalf + (cb << 4) + l15;
            float bth = b0[co], bph = b1[co], bg = b2[co];
            int pixb = (row << 6) + wb0 + (quad << 2);
#pragma unroll
            for (int r = 0; r < 4; ++r) {
                size_t off = (((size_t)(pixb + r)) << 6) + co;
                float v = acc[0][cb][r] + bth;
                ushort hh = f2bf(v);
                o0h[off] = hh;
                o0l[off] = f2bf(v - bf2f(hh));
                v = acc[1][cb][r] + bph;
                hh = f2bf(v);
                o1h[off] = hh;
                o1l[off] = f2bf(v - bf2f(hh));
            }
            int n0 = pixb & 4095;
            ushort4 gv;
            gv.x = f2bf(acc[2][cb][0] + bg);
            gv.y = f2bf(acc[2][cb][1] + bg);
            gv.z = f2bf(acc[2][cb][2] + bg);
            gv.w = f2bf(acc[2][cb][3] + bg);
            *(ushort4*)&o2t[(((size_t)b) << 18) + (((size_t)co) << 12) + n0] = gv;
        }
    }
}

// ---------------------------------------------------------------------------
// statsB: reduce 512 block-partials per channel -> BN scale/shift.
// ---------------------------------------------------------------------------
__global__ __launch_bounds__(256) void statsB_k(
    const float* __restrict__ part, const float* __restrict__ gamma,
    const float* __restrict__ beta, float* __restrict__ scale,
    float* __restrict__ shift)
{
    __shared__ float rs[4][64], rss[4][64];
    const int t = threadIdx.x, c = t & 63, seg = t >> 6;
    float S = 0.f, SS = 0.f;
    for (int k = seg * 128; k < seg * 128 + 128; ++k) {
        S += part[k * 64 + c];
        SS += part[32768 + k * 64 + c];
    }
    rs[seg][c] = S;
    rss[seg][c] = SS;
    __syncthreads();
    if (t < 64) {
        float Sf = rs[0][t] + rs[1][t] + rs[2][t] + rs[3][t];
        float SSf = rss[0][t] + rss[1][t] + rss[2][t] + rss[3][t];
        float mean = Sf * (1.f / 16384.f);
        float var = SSf * (1.f / 16384.f) - mean * mean;
        float sc = gamma[t] * rsqrtf(var + 1e-5f);
        scale[t] = sc;
        shift[t] = beta[t] - mean * sc;
    }
}

// ---------------------------------------------------------------------------
// x1prep: c1T fp32 [pix][ch] -> relu(BN) -> x1T bf16 hi/lo.
// ---------------------------------------------------------------------------
__global__ __launch_bounds__(256) void x1prep_k(
    const float* __restrict__ c1T, const float* __restrict__ sc,
    const float* __restrict__ sh, ushort* __restrict__ xh,
    ushort* __restrict__ xl)
{
    int p = blockIdx.x * 256 + threadIdx.x;  // < 262144
    int c4 = (p & 15) << 2;
    float4 v = *(const float4*)&c1T[(size_t)p << 2];
    float4 s4 = *(const float4*)&sc[c4];
    float4 h4 = *(const float4*)&sh[c4];
    float r0 = fmaxf(v.x * s4.x + h4.x, 0.f);
    float r1 = fmaxf(v.y * s4.y + h4.y, 0.f);
    float r2 = fmaxf(v.z * s4.z + h4.z, 0.f);
    float r3 = fmaxf(v.w * s4.w + h4.w, 0.f);
    ushort4 hi, lo;
    hi.x = f2bf(r0); lo.x = f2bf(r0 - bf2f(hi.x));
    hi.y = f2bf(r1); lo.y = f2bf(r1 - bf2f(hi.y));
    hi.z = f2bf(r2); lo.z = f2bf(r2 - bf2f(hi.z));
    hi.w = f2bf(r3); lo.w = f2bf(r3 - bf2f(hi.w));
    *(ushort4*)&xh[(size_t)p << 2] = hi;
    *(ushort4*)&xl[(size_t)p << 2] = lo;
}

// ---------------------------------------------------------------------------
// Flash attention: r7's proven structure (coalesced LDS staging + register
// prefetch, Q frags hoisted from global, 2-way KV split + XCD swizzle,
// static max M=30), minus the K-lo term (validated in r8: absmax unchanged).
// S = (Qhi+Qlo)·Khi. LDS: Khi 8K + V 2x8K + P 8K = 32 KB. 2 barriers/step.
// Outputs partial O fp32 [pix][ch] + partial l.
// ---------------------------------------------------------------------------
__device__ __forceinline__ short8 ldfrag(const ushort* base, int row, int ch) {
    return *(const short8*)&base[(row << 6) + (((ch ^ (row & 7))) << 3)];
}

__global__ __launch_bounds__(256) void attn_k(
    const ushort* __restrict__ thT_hi, const ushort* __restrict__ thT_lo,
    const ushort* __restrict__ phT_hi, const ushort* __restrict__ phT_lo,
    const ushort* __restrict__ g16, float* __restrict__ O0,
    float* __restrict__ O1, float* __restrict__ lp)
{
    __shared__ __align__(16) ushort Khi[4096];
    __shared__ __align__(16) ushort Vt[2][4096];
    __shared__ __align__(16) ushort Pt[4096];

    const int t = threadIdx.x;
    const int bx = blockIdx.x;
    const int xslot = bx & 7;
    const int b = xslot & 3;
    const int half = xslot >> 2;
    const int q0 = (bx >> 3) << 6;
    const int mbase = half << 11;
    const int lane = t & 63;
    const int wv = t >> 6;
    const int quad = lane >> 4;
    const int l15 = lane & 15;
    const int rhalf = (wv >> 1) << 5;
    const int chalf = (wv & 1) << 5;

    const size_t cb64 = ((size_t)b) << 18;
    const ushort* Qh_g = thT_hi + cb64 + (((size_t)q0) << 6);
    const ushort* Ql_g = thT_lo + cb64 + (((size_t)q0) << 6);
    const ushort* Kh_g = phT_hi + cb64;
    const ushort* Vg = g16 + cb64;
    float* Op = half ? O1 : O0;
    float* lpd = lp + (half << 14);
    (void)phT_lo;

    // hoisted Q A-frags straight from global (step-invariant)
    short8 aHi[2][2], aLo[2][2];
#pragma unroll
    for (int rb = 0; rb < 2; ++rb)
#pragma unroll
        for (int ks = 0; ks < 2; ++ks) {
            size_t off = (((size_t)(rhalf + (rb << 4) + l15)) << 6) +
                         ks * 32 + quad * 8;
            aHi[rb][ks] = *(const short8*)&Qh_g[off];
            aLo[rb][ks] = *(const short8*)&Ql_g[off];
        }

    // initial staging: step-0 K/V
#pragma unroll
    for (int rd = 0; rd < 2; ++rd) {
        int ii = rd * 256 + t;
        int row = ii >> 3, ch = ii & 7;
        int off = (row << 6) + ((ch ^ (row & 7)) << 3);
        *(short8*)&Khi[off] = *(const short8*)&Kh_g[((mbase + row) << 6) + (ch << 3)];
        *(short8*)&Vt[0][off] = *(const short8*)&Vg[(row << 12) + mbase + (ch << 3)];
    }

    f32x4 oacc[2][2];
    f32x4 lacc[2];
#pragma unroll
    for (int rb = 0; rb < 2; ++rb) {
#pragma unroll
        for (int j = 0; j < 4; ++j) lacc[rb][j] = 0.f;
#pragma unroll
        for (int cb = 0; cb < 2; ++cb)
#pragma unroll
            for (int j = 0; j < 4; ++j) oacc[rb][cb][j] = 0.f;
    }
    short8 onesB;
    {
        short ov = (l15 == 0) ? (short)0x3F80 : (short)0;
#pragma unroll
        for (int j = 0; j < 8; ++j) onesB[j] = ov;
    }

    for (int step = 0; step < 32; ++step) {
        const int buf = step & 1;
        __syncthreads();  // K/V(step) visible; P(step-1) consumers done

        short8 rKh[2], rV[2];
        if (step < 31) {
            const int m1 = mbase + ((step + 1) << 6);
#pragma unroll
            for (int rd = 0; rd < 2; ++rd) {
                int ii = rd * 256 + t;
                int row = ii >> 3, ch = ii & 7;
                rKh[rd] = *(const short8*)&Kh_g[((m1 + row) << 6) + (ch << 3)];
                rV[rd] = *(const short8*)&Vg[(row << 12) + m1 + (ch << 3)];
            }
        }

        short8 bHi[2][2];
#pragma unroll
        for (int cb = 0; cb < 2; ++cb) {
            int row = chalf + (cb << 4) + l15;
#pragma unroll
            for (int ks = 0; ks < 2; ++ks)
                bHi[cb][ks] = ldfrag(Khi, row, (ks << 2) + quad);
        }
        f32x4 sacc[2][2];
#pragma unroll
        for (int rb = 0; rb < 2; ++rb)
#pragma unroll
            for (int cb = 0; cb < 2; ++cb)
#pragma unroll
                for (int j = 0; j < 4; ++j) sacc[rb][cb][j] = 0.f;
#pragma unroll
        for (int ks = 0; ks < 2; ++ks)
#pragma unroll
            for (int rb = 0; rb < 2; ++rb)
#pragma unroll
                for (int cb = 0; cb < 2; ++cb) {
                    sacc[rb][cb] = __builtin_amdgcn_mfma_f32_16x16x32_bf16(
                        aHi[rb][ks], bHi[cb][ks], sacc[rb][cb], 0, 0, 0);
                    sacc[rb][cb] = __builtin_amdgcn_mfma_f32_16x16x32_bf16(
                        aLo[rb][ks], bHi[cb][ks], sacc[rb][cb], 0, 0, 0);
                }
#pragma unroll
        for (int rb = 0; rb < 2; ++rb)
#pragma unroll
            for (int cb = 0; cb < 2; ++cb) {
                int pcol = chalf + (cb << 4) + l15;
#pragma unroll
                for (int r = 0; r < 4; ++r) {
                    int prow = rhalf + (rb << 4) + (quad << 2) + r;
                    float p = __expf(sacc[rb][cb][r] - 30.f);
                    Pt[(prow << 6) + (((pcol >> 3) ^ (prow & 7)) << 3) +
                       (pcol & 7)] = f2bf(p);
                }
            }
        __syncthreads();  // P visible; all S-phase K reads done

        short8 pa[2][2], vb[2][2];
#pragma unroll
        for (int rb = 0; rb < 2; ++rb) {
            int row = rhalf + (rb << 4) + l15;
#pragma unroll
            for (int ks = 0; ks < 2; ++ks)
                pa[rb][ks] = ldfrag(Pt, row, (ks << 2) + quad);
        }
#pragma unroll
        for (int cb = 0; cb < 2; ++cb) {
            int row = chalf + (cb << 4) + l15;
#pragma unroll
            for (int ks = 0; ks < 2; ++ks)
                vb[cb][ks] = ldfrag(&Vt[buf][0], row, (ks << 2) + quad);
        }
#pragma unroll
        for (int ks = 0; ks < 2; ++ks)
#pragma unroll
            for (int rb = 0; rb < 2; ++rb)
#pragma unroll
                for (int cb = 0; cb < 2; ++cb)
                    oacc[rb][cb] = __builtin_amdgcn_mfma_f32_16x16x32_bf16(
                        pa[rb][ks], vb[cb][ks], oacc[rb][cb], 0, 0, 0);
#pragma unroll
        for (int rb = 0; rb < 2; ++rb)
#pragma unroll
            for (int ks = 0; ks < 2; ++ks)
                lacc[rb] = __builtin_amdgcn_mfma_f32_16x16x32_bf16(
                    pa[rb][ks], onesB, lacc[rb], 0, 0, 0);

        if (step < 31) {
#pragma unroll
            for (int rd = 0; rd < 2; ++rd) {
                int ii = rd * 256 + t;
                int row = ii >> 3, ch = ii & 7;
                int off = (row << 6) + ((ch ^ (row & 7)) << 3);
                *(short8*)&Khi[off] = rKh[rd];
                *(short8*)&Vt[buf ^ 1][off] = rV[rd];
            }
        }
    }

    // epilogue: write partial l (col-0 lanes) and partial O (no division)
#pragma unroll
    for (int rb = 0; rb < 2; ++rb) {
        if ((wv & 1) == 0 && l15 == 0) {
#pragma unroll
            for (int r = 0; r < 4; ++r) {
                int nn = q0 + rhalf + (rb << 4) + (quad << 2) + r;
                lpd[(b << 12) + nn] = lacc[rb][r];
            }
        }
#pragma unroll
        for (int cb = 0; cb < 2; ++cb) {
            int cc = chalf + (cb << 4) + l15;
#pragma unroll
            for (int r = 0; r < 4; ++r) {
                int nn = q0 + rhalf + (rb << 4) + (quad << 2) + r;
                Op[cb64 + (((size_t)nn) << 6) + cc] = oacc[rb][cb][r];
            }
        }
    }
}

// ---------------------------------------------------------------------------
// 1x1 conv + bias + residual, MFMA (W-hi only), with FUSED attention reduce:
// y = (O0+O1)/(l0+l1) built in-register as bf16 hi/lo A-frags.
// ---------------------------------------------------------------------------
__global__ __launch_bounds__(256) void conv1x1_k(
    const float* __restrict__ O0, const float* __restrict__ O1,
    const float* __restrict__ lp,
    const ushort* __restrict__ wh,
    const float* __restrict__ Wb, const float* __restrict__ x,
    ushort* __restrict__ zh, ushort* __restrict__ zl)
{
    const int t = threadIdx.x, lane = t & 63, wv = t >> 6;
    const int quad = lane >> 4, l15 = lane & 15;
    const int chalf = (wv & 1) << 5;
    const int P0 = blockIdx.x << 5;
    const int pbase = P0 + ((wv >> 1) << 4);
    const int b = P0 >> 12;
    const int pix = pbase + l15;   // A row
    const int nn = pix & 4095;
    const float linv = 1.f / (lp[(b << 12) + nn] + lp[16384 + (b << 12) + nn]);

    f32x4 acc[2];
#pragma unroll
    for (int j = 0; j < 4; ++j) { acc[0][j] = 0.f; acc[1][j] = 0.f; }

#pragma unroll
    for (int kc = 0; kc < 2; ++kc) {
        const int k0 = kc * 32 + quad * 8;
        size_t ao = (((size_t)pix) << 6) + k0;
        float4 a0 = *(const float4*)&O0[ao];
        float4 a1 = *(const float4*)&O0[ao + 4];
        float4 c0 = *(const float4*)&O1[ao];
        float4 c1 = *(const float4*)&O1[ao + 4];
        float v[8] = {(a0.x + c0.x) * linv, (a0.y + c0.y) * linv,
                      (a0.z + c0.z) * linv, (a0.w + c0.w) * linv,
                      (a1.x + c1.x) * linv, (a1.y + c1.y) * linv,
                      (a1.z + c1.z) * linv, (a1.w + c1.w) * linv};
        short8 aH, aL;
#pragma unroll
        for (int j = 0; j < 8; ++j) {
            ushort hh = f2bf(v[j]);
            aH[j] = (short)hh;
            aL[j] = (short)f2bf(v[j] - bf2f(hh));
        }
#pragma unroll
        for (int cb = 0; cb < 2; ++cb) {
            int co = chalf + (cb << 4) + l15;
            short8 bH = *(const short8*)&wh[(((size_t)co) << 6) + k0];
            acc[cb] = __builtin_amdgcn_mfma_f32_16x16x32_bf16(aH, bH, acc[cb], 0, 0, 0);
            acc[cb] = __builtin_amdgcn_mfma_f32_16x16x32_bf16(aL, bH, acc[cb], 0, 0, 0);
        }
    }

    const int pixb = pbase + (quad << 2);
    const int n0 = pixb & 4095;
#pragma unroll
    for (int cb = 0; cb < 2; ++cb) {
        int co = chalf + (cb << 4) + l15;
        float bias = Wb[co];
        float4 xr = *(const float4*)&x[(((size_t)(b * 64 + co)) << 12) + n0];
        float xa[4] = {xr.x, xr.y, xr.z, xr.w};
#pragma unroll
        for (int r = 0; r < 4; ++r) {
            float v = acc[cb][r] + bias + xa[r];
            size_t off = (((size_t)(pixb + r)) << 6) + co;
            ushort hh = f2bf(v);
            zh[off] = hh;
            zl[off] = f2bf(v - bf2f(hh));
        }
    }
}

// ---------------------------------------------------------------------------
// Final: BN2 apply + relu + transpose back to [B][C][H][W].
// ---------------------------------------------------------------------------
__global__ __launch_bounds__(256) void bnreluT_k(
    const float* __restrict__ c2T, const float* __restrict__ sc,
    const float* __restrict__ sh, float* __restrict__ out)
{
    __shared__ __align__(16) float T[64 * 68];
    const int b = blockIdx.x >> 6, n0 = (blockIdx.x & 63) << 6, t = threadIdx.x;
    for (int p = t; p < 1024; p += 256) {
        int n = p >> 4, c4 = (p & 15) << 2;
        float4 v = *(const float4*)&c2T[(((size_t)(b * 4096 + n0 + n)) << 6) + c4];
        float4 s4 = *(const float4*)&sc[c4];
        float4 h4 = *(const float4*)&sh[c4];
        T[(c4 + 0) * 68 + n] = fmaxf(v.x * s4.x + h4.x, 0.f);
        T[(c4 + 1) * 68 + n] = fmaxf(v.y * s4.y + h4.y, 0.f);
        T[(c4 + 2) * 68 + n] = fmaxf(v.z * s4.z + h4.z, 0.f);
        T[(c4 + 3) * 68 + n] = fmaxf(v.w * s4.w + h4.w, 0.f);
    }
    __syncthreads();
    for (int p = t; p < 1024; p += 256) {
        int c = p >> 4, n4 = (p & 15) << 2;
        float4 r;
        r.x = T[c * 68 + n4 + 0];
        r.y = T[c * 68 + n4 + 1];
        r.z = T[c * 68 + n4 + 2];
        r.w = T[c * 68 + n4 + 3];
        *(float4*)&out[(((size_t)(b * 64 + c)) << 12) + n0 + n4] = r;
    }
}

// ---------------------------------------------------------------------------
extern "C" void kernel_launch(void* const* d_in, const int* in_sizes, int n_in,
                              void* d_out, int out_size, void* d_ws,
                              size_t ws_size, hipStream_t stream)
{
    const float* x    = (const float*)d_in[0];
    const float* c1w  = (const float*)d_in[1];
    const float* bn1g = (const float*)d_in[2];
    const float* bn1b = (const float*)d_in[3];
    const float* thw  = (const float*)d_in[4];
    const float* thb  = (const float*)d_in[5];
    const float* phw  = (const float*)d_in[6];
    const float* phb  = (const float*)d_in[7];
    const float* gw   = (const float*)d_in[8];
    const float* gb   = (const float*)d_in[9];
    const float* Wwt  = (const float*)d_in[10];
    const float* Wbs  = (const float*)d_in[11];
    const float* c2w  = (const float*)d_in[12];
    const float* bn2g = (const float*)d_in[13];
    const float* bn2b = (const float*)d_in[14];
    float* out = (float*)d_out;

    float* ws = (float*)d_ws;
    // region A: xT/x1T hi+lo -> O0 fp32 -> c2T fp32
    ushort* xT_hi = (ushort*)ws;
    ushort* xT_lo = xT_hi + (1 << 20);
    ushort* x1T_hi = xT_hi;
    ushort* x1T_lo = xT_lo;
    float* O0 = ws;
    float* c2T = ws;
    // region B: c1T fp32 -> O1 fp32
    float* c1T = ws + (1 << 20);
    float* O1 = c1T;
    // region C: thT hi/lo -> zT hi/lo
    ushort* thT_hi = (ushort*)(ws + (2 << 20));
    ushort* thT_lo = thT_hi + (1 << 20);
    ushort* zT_hi = thT_hi;
    ushort* zT_lo = thT_lo;
    // regions D/E
    ushort* phT_hi = (ushort*)(ws + (3 << 20));
    ushort* phT_lo = phT_hi + (1 << 20);
    ushort* g16 = (ushort*)(ws + (4 << 20));
    // weights / partials / stats
    ushort* wp = (ushort*)(ws + (9 << 19));
    float* part = ws + (5 << 20) - 65536;  // also lp for attention
    float* stats = ws + (5 << 20);
    float* sc1 = stats, *sh1 = stats + 64, *sc2 = stats + 128, *sh2 = stats + 192;

    ushort* wc1h = wp;
    ushort* wthh = wp + 1 * 73728;
    ushort* wphh = wp + 2 * 73728;
    ushort* wgh  = wp + 3 * 73728;
    ushort* wc2h = wp + 4 * 73728;
    ushort* w11h = wp + 5 * 73728;

    prep_all_k<<<992, 256, 0, stream>>>(x, xT_hi, xT_lo, c1w, thw, phw, gw,
                                        c2w, Wwt, wp);
    conv_mfma_k<1, 0><<<512, 256, 0, stream>>>(
        xT_hi, xT_lo, wc1h, nullptr, nullptr, nullptr, nullptr, nullptr,
        c1T, part, nullptr, nullptr, nullptr, nullptr, nullptr);
    statsB_k<<<1, 256, 0, stream>>>(part, bn1g, bn1b, sc1, sh1);
    x1prep_k<<<1024, 256, 0, stream>>>(c1T, sc1, sh1, x1T_hi, x1T_lo);
    conv_mfma_k<3, 1><<<512, 256, 0, stream>>>(
        x1T_hi, x1T_lo, wthh, wphh, wgh, thb, phb, gb,
        nullptr, nullptr, thT_hi, thT_lo, phT_hi, phT_lo, g16);
    attn_k<<<512, 256, 0, stream>>>(thT_hi, thT_lo, phT_hi, phT_lo, g16,
                                    O0, O1, part);
    conv1x1_k<<<512, 256, 0, stream>>>(O0, O1, part, w11h, Wbs, x,
                                       zT_hi, zT_lo);
    conv_mfma_k<1, 0><<<512, 256, 0, stream>>>(
        zT_hi, zT_lo, wc2h, nullptr, nullptr, nullptr, nullptr, nullptr,
        c2T, part, nullptr, nullptr, nullptr, nullptr, nullptr);
    statsB_k<<<1, 256, 0, stream>>>(part, bn2g, bn2b, sc2, sh2);
    bnreluT_k<<<256, 256, 0, stream>>>(c2T, sc2, sh2, out);
}

// Round 11
// 237.450 us; speedup vs baseline: 1.1882x; 1.0005x over previous
//
#include <hip/hip_runtime.h>
#include <math.h>

// B=4, C=64, H=W=64, N=4096, NPIX=16384. All fp32 in/out.
// Pixel-major [pix][ch] bf16 hi/lo pipeline. ws (floats), footprint 5M+256:
//  A ws+0..1M   : xT hi/lo -> x1T hi/lo -> O0 (attn partial fp32) -> c2T fp32
//  B ws+1M..2M  : c1T fp32 -> O1 (attn partial fp32)
//  C ws+2M..3M  : thT hi/lo -> zT hi/lo
//  D ws+3M..4M  : phT hi (lo slot unused)
//  E ws+4M..4.5M: g16 (bf16 [B][C][N])
//  wp ws+4.5M   : prepped weights ; part/lp ws+5M-65536 ; stats ws+5M

typedef __attribute__((ext_vector_type(8))) short short8;
typedef __attribute__((ext_vector_type(4))) short short4v;
typedef __attribute__((ext_vector_type(4))) float f32x4;

#if defined(__has_builtin)
#if __has_builtin(__builtin_amdgcn_mfma_f32_16x16x16bf16_1k)
#define HAVE_BF16_K16 1
#endif
#endif

__device__ __forceinline__ ushort f2bf(float x) {
    unsigned u = __float_as_uint(x);
    unsigned r = (u + 0x7FFFu + ((u >> 16) & 1u)) >> 16;  // RNE
    return (ushort)r;
}
__device__ __forceinline__ float bf2f(ushort h) {
    return __uint_as_float(((unsigned)h) << 16);
}

// ---------------------------------------------------------------------------
// prep_all: blocks <256: x -> xT [pix][ch] bf16 hi/lo. blocks >=256: weights.
// ---------------------------------------------------------------------------
__global__ __launch_bounds__(256) void prep_all_k(
    const float* __restrict__ x, ushort* __restrict__ xh,
    ushort* __restrict__ xl,
    const float* __restrict__ w0, const float* __restrict__ w1,
    const float* __restrict__ w2, const float* __restrict__ w3,
    const float* __restrict__ w4, const float* __restrict__ w5,
    ushort* __restrict__ wbase)
{
    __shared__ __align__(16) float T[64 * 68];
    const int blk = blockIdx.x, t = threadIdx.x;
    if (blk < 256) {
        const int b = blk >> 6, n0 = (blk & 63) << 6;
        for (int p = t; p < 1024; p += 256) {
            int c = p >> 4, n4 = (p & 15) << 2;
            *(float4*)&T[c * 68 + n4] =
                *(const float4*)&x[(((size_t)(b * 64 + c)) << 12) + n0 + n4];
        }
        __syncthreads();
        for (int p = t; p < 1024; p += 256) {
            int n = p >> 4, c4 = (p & 15) << 2;
            size_t off = (((size_t)(b * 4096 + n0 + n)) << 6) + c4;
            ushort4 hi, lo;
            float v;
            v = T[(c4 + 0) * 68 + n]; hi.x = f2bf(v); lo.x = f2bf(v - bf2f(hi.x));
            v = T[(c4 + 1) * 68 + n]; hi.y = f2bf(v); lo.y = f2bf(v - bf2f(hi.y));
            v = T[(c4 + 2) * 68 + n]; hi.z = f2bf(v); lo.z = f2bf(v - bf2f(hi.z));
            v = T[(c4 + 3) * 68 + n]; hi.w = f2bf(v); lo.w = f2bf(v - bf2f(hi.w));
            *(ushort4*)&xh[off] = hi;
            *(ushort4*)&xl[off] = lo;
        }
    } else {
        const float* W[6] = {w0, w1, w2, w3, w4, w5};
        int q = blk - 256;
        if (q < 720) {
            int s = q / 144, bi = q - s * 144;
            int idx = bi * 256 + t;
            if (idx >= 36864) return;
            int co = idx / 576;
            int r = idx - co * 576;
            int ci = r / 9;
            int tap = r - ci * 9;
            float v = W[s][idx];
            ushort* hi = wbase + (size_t)s * 73728;
            ushort* lo = hi + 36864;
            int off = tap * 4096 + co * 64 + ci;
            ushort h = f2bf(v);
            hi[off] = h;
            lo[off] = f2bf(v - bf2f(h));
        } else {
            int idx = (q - 720) * 256 + t;
            if (idx >= 4096) return;
            float v = W[5][idx];
            ushort* hi = wbase + 5 * 73728;
            ushort* lo = hi + 4096;
            ushort h = f2bf(v);
            hi[idx] = h;
            lo[idx] = f2bf(v - bf2f(h));
        }
    }
}

// ---------------------------------------------------------------------------
// MFMA 3x3 conv. Block = 32 pix x 64 co, grid 512 (2 blk/CU). Wave tile
// 16pix x 32co. A hi/lo compensated; W hi ONLY (r9-validated).
// MODE 0: fp32 out [pix][co] + fused BN partial stats -> part[bx*64+ch].
// MODE 1 (NOUT=3): theta -> hi/lo; phi -> hi ONLY (lo never read);
//                  g -> bf16 [B][co][n].
// ---------------------------------------------------------------------------
template <int NOUT, int MODE>
__global__ __launch_bounds__(256) void conv_mfma_k(
    const ushort* __restrict__ Ah, const ushort* __restrict__ Al,
    const ushort* __restrict__ w0h, const ushort* __restrict__ w1h,
    const ushort* __restrict__ w2h,
    const float* __restrict__ b0, const float* __restrict__ b1,
    const float* __restrict__ b2,
    float* __restrict__ outF, float* __restrict__ part,
    ushort* __restrict__ o0h, ushort* __restrict__ o0l,
    ushort* __restrict__ o1h,
    ushort* __restrict__ o2t)
{
    __shared__ float redS[4][32], redSS[4][32];
    const int t = threadIdx.x, lane = t & 63, wv = t >> 6;
    const int quad = lane >> 4, l15 = lane & 15;
    const int bx = blockIdx.x;
    const int row = bx >> 1;                            // b*64 + h
    const int h = row & 63;
    const int wb0 = ((bx & 1) << 5) + ((wv >> 1) << 4); // wave pixel base (w)
    const int chalf = (wv & 1) << 5;

    const ushort* wh[3] = {w0h, w1h, w2h};

    f32x4 acc[NOUT][2];
#pragma unroll
    for (int o = 0; o < NOUT; ++o)
#pragma unroll
        for (int cb = 0; cb < 2; ++cb)
#pragma unroll
            for (int j = 0; j < 4; ++j) acc[o][cb][j] = 0.f;

#pragma unroll
    for (int dh = -1; dh <= 1; ++dh) {
        if ((unsigned)(h + dh) >= 64u) continue;  // block-uniform
#pragma unroll
        for (int dw = -1; dw <= 1; ++dw) {
            const int tap = (dh + 1) * 3 + (dw + 1);
#pragma unroll
            for (int kc = 0; kc < 2; ++kc) {
                const int k0 = kc * 32 + quad * 8;
                const int sw = wb0 + l15 + dw;
                short8 aH = {0, 0, 0, 0, 0, 0, 0, 0};
                short8 aL = {0, 0, 0, 0, 0, 0, 0, 0};
                if ((unsigned)sw < 64u) {
                    size_t off = (((size_t)(((row + dh) << 6) + sw)) << 6) + k0;
                    aH = *(const short8*)&Ah[off];
                    aL = *(const short8*)&Al[off];
                }
#pragma unroll
                for (int o = 0; o < NOUT; ++o)
#pragma unroll
                    for (int cb = 0; cb < 2; ++cb) {
                        int co = chalf + (cb << 4) + l15;
                        short8 bH = *(const short8*)
                            &wh[o][(((size_t)tap) << 12) + (((size_t)co) << 6) + k0];
                        acc[o][cb] = __builtin_amdgcn_mfma_f32_16x16x32_bf16(
                            aH, bH, acc[o][cb], 0, 0, 0);
                        acc[o][cb] = __builtin_amdgcn_mfma_f32_16x16x32_bf16(
                            aL, bH, acc[o][cb], 0, 0, 0);
                    }
            }
        }
    }

    if (MODE == 0) {
        float s_[2], ss_[2];
#pragma unroll
        for (int cb = 0; cb < 2; ++cb) {
            int co = chalf + (cb << 4) + l15;
            float s = 0.f, ss = 0.f;
#pragma unroll
            for (int r = 0; r < 4; ++r) {
                int pix = (row << 6) + wb0 + (quad << 2) + r;
                float v = acc[0][cb][r];
                outF[(((size_t)pix) << 6) + co] = v;
                s += v;
                ss += v * v;
            }
            s_[cb] = s;
            ss_[cb] = ss;
        }
#pragma unroll
        for (int off = 16; off < 64; off <<= 1) {
#pragma unroll
            for (int cb = 0; cb < 2; ++cb) {
                s_[cb] += __shfl_xor(s_[cb], off);
                ss_[cb] += __shfl_xor(ss_[cb], off);
            }
        }
        if (quad == 0) {
#pragma unroll
            for (int cb = 0; cb < 2; ++cb) {
                redS[wv][(cb << 4) + l15] = s_[cb];
                redSS[wv][(cb << 4) + l15] = ss_[cb];
            }
        }
        __syncthreads();
        if (t < 64) {
            int w01 = (t >> 5) & 1;  // chalf bit
            float S = redS[w01][t & 31] + redS[w01 + 2][t & 31];
            float SS = redSS[w01][t & 31] + redSS[w01 + 2][t & 31];
            part[bx * 64 + t] = S;
            part[32768 + bx * 64 + t] = SS;
        }
    } else {
        const int b = row >> 6;
#pragma unroll
        for (int cb = 0; cb < 2; ++cb) {
            int co = chalf + (cb << 4) + l15;
            float bth = b0[co], bph = b1[co], bg = b2[co];
            int pixb = (row << 6) + wb0 + (quad << 2);
#pragma unroll
            for (int r = 0; r < 4; ++r) {
                size_t off = (((size_t)(pixb + r)) << 6) + co;
                float v = acc[0][cb][r] + bth;
                ushort hh = f2bf(v);
                o0h[off] = hh;
                o0l[off] = f2bf(v - bf2f(hh));
                o1h[off] = f2bf(acc[1][cb][r] + bph);  // phi hi only
            }
            int n0 = pixb & 4095;
            ushort4 gv;
            gv.x = f2bf(acc[2][cb][0] + bg);
            gv.y = f2bf(acc[2][cb][1] + bg);
            gv.z = f2bf(acc[2][cb][2] + bg);
            gv.w = f2bf(acc[2][cb][3] + bg);
            *(ushort4*)&o2t[(((size_t)b) << 18) + (((size_t)co) << 12) + n0] = gv;
        }
    }
}

// ---------------------------------------------------------------------------
// statsB: reduce 512 block-partials per channel -> BN scale/shift.
// ---------------------------------------------------------------------------
__global__ __launch_bounds__(256) void statsB_k(
    const float* __restrict__ part, const float* __restrict__ gamma,
    const float* __restrict__ beta, float* __restrict__ scale,
    float* __restrict__ shift)
{
    __shared__ float rs[4][64], rss[4][64];
    const int t = threadIdx.x, c = t & 63, seg = t >> 6;
    float S = 0.f, SS = 0.f;
    for (int k = seg * 128; k < seg * 128 + 128; ++k) {
        S += part[k * 64 + c];
        SS += part[32768 + k * 64 + c];
    }
    rs[seg][c] = S;
    rss[seg][c] = SS;
    __syncthreads();
    if (t < 64) {
        float Sf = rs[0][t] + rs[1][t] + rs[2][t] + rs[3][t];
        float SSf = rss[0][t] + rss[1][t] + rss[2][t] + rss[3][t];
        float mean = Sf * (1.f / 16384.f);
        float var = SSf * (1.f / 16384.f) - mean * mean;
        float sc = gamma[t] * rsqrtf(var + 1e-5f);
        scale[t] = sc;
        shift[t] = beta[t] - mean * sc;
    }
}

// ---------------------------------------------------------------------------
// x1prep: c1T fp32 [pix][ch] -> relu(BN) -> x1T bf16 hi/lo.
// ---------------------------------------------------------------------------
__global__ __launch_bounds__(256) void x1prep_k(
    const float* __restrict__ c1T, const float* __restrict__ sc,
    const float* __restrict__ sh, ushort* __restrict__ xh,
    ushort* __restrict__ xl)
{
    int p = blockIdx.x * 256 + threadIdx.x;  // < 262144
    int c4 = (p & 15) << 2;
    float4 v = *(const float4*)&c1T[(size_t)p << 2];
    float4 s4 = *(const float4*)&sc[c4];
    float4 h4 = *(const float4*)&sh[c4];
    float r0 = fmaxf(v.x * s4.x + h4.x, 0.f);
    float r1 = fmaxf(v.y * s4.y + h4.y, 0.f);
    float r2 = fmaxf(v.z * s4.z + h4.z, 0.f);
    float r3 = fmaxf(v.w * s4.w + h4.w, 0.f);
    ushort4 hi, lo;
    hi.x = f2bf(r0); lo.x = f2bf(r0 - bf2f(hi.x));
    hi.y = f2bf(r1); lo.y = f2bf(r1 - bf2f(hi.y));
    hi.z = f2bf(r2); lo.z = f2bf(r2 - bf2f(hi.z));
    hi.w = f2bf(r3); lo.w = f2bf(r3 - bf2f(hi.w));
    *(ushort4*)&xh[(size_t)p << 2] = hi;
    *(ushort4*)&xl[(size_t)p << 2] = lo;
}

__device__ __forceinline__ short8 ldfrag(const ushort* base, int row, int ch) {
    return *(const short8*)&base[(row << 6) + (((ch ^ (row & 7))) << 3)];
}

#ifdef HAVE_BF16_K16
// ---------------------------------------------------------------------------
// Flash attention v11: S^T formulation with bf16 K=16 PV (range-safe).
// S^T = K x Q^T (16x16x32 bf16, A = K from LDS, B = Q hi+lo from global).
// sacc's C-layout (col=lane&15=q, row=quad*4+r=m) IS the B-operand layout
// of the K=16 MFMA -> P feeds PV from REGISTERS (no P LDS round-trip).
// P = exp(s-30) in bf16 (r9-proven numerics; bf16 range -> no MFMA denormal
// flush, the r10 f16 failure mode). PV: O^T += V^T x P^T via
// mfma_f32_16x16x16bf16_1k; V bf16 in pad-72 LDS. K/V double-buffered,
// 1 barrier/step. Waves split q(2) x m(2); one-time cross-wave O/l reduce.
// 2-way KV split + XCD swizzle. LDS 34 KB. Partial O fp32 + l out.
// ---------------------------------------------------------------------------
__global__ __launch_bounds__(256) void attn_st_k(
    const ushort* __restrict__ thT_hi, const ushort* __restrict__ thT_lo,
    const ushort* __restrict__ phT_hi, const ushort* __restrict__ phT_lo,
    const ushort* __restrict__ g16, float* __restrict__ O0,
    float* __restrict__ O1, float* __restrict__ lp)
{
    __shared__ __align__(16) ushort Khi[2][4096];
    __shared__ __align__(16) ushort Vt[2][64 * 72];  // bf16, pad-72 rows

    const int t = threadIdx.x;
    const int bx = blockIdx.x;
    const int xslot = bx & 7;
    const int b = xslot & 3;
    const int half = xslot >> 2;
    const int q0 = (bx >> 3) << 6;
    const int mbase = half << 11;
    const int lane = t & 63;
    const int wv = t >> 6;
    const int quad = lane >> 4;
    const int l15 = lane & 15;
    const int qw = wv & 1;    // q 32-half
    const int mw = wv >> 1;   // m 32-half of each 64-step

    const size_t cb64 = ((size_t)b) << 18;
    const ushort* Qh_g = thT_hi + cb64 + (((size_t)q0) << 6);
    const ushort* Ql_g = thT_lo + cb64 + (((size_t)q0) << 6);
    const ushort* Kh_g = phT_hi + cb64;
    const ushort* Vg = g16 + cb64;
    float* Op = half ? O1 : O0;
    float* lpd = lp + (half << 14);
    (void)phT_lo;

    // hoisted Q B-frags (B[k=c][n=q], step-invariant)
    short8 qHi[2][2], qLo[2][2];  // [qt][ks]
#pragma unroll
    for (int qt = 0; qt < 2; ++qt)
#pragma unroll
        for (int ks = 0; ks < 2; ++ks) {
            size_t off = (((size_t)(qw * 32 + qt * 16 + l15)) << 6) +
                         ks * 32 + quad * 8;
            qHi[qt][ks] = *(const short8*)&Qh_g[off];
            qLo[qt][ks] = *(const short8*)&Ql_g[off];
        }

    // initial staging: step-0 K/V into buf 0
#pragma unroll
    for (int rd = 0; rd < 2; ++rd) {
        int ii = rd * 256 + t;
        int row = ii >> 3, ch = ii & 7;
        *(short8*)&Khi[0][(row << 6) + ((ch ^ (row & 7)) << 3)] =
            *(const short8*)&Kh_g[((mbase + row) << 6) + (ch << 3)];
        *(short8*)&Vt[0][row * 72 + (ch << 3)] =
            *(const short8*)&Vg[(row << 12) + mbase + (ch << 3)];
    }
    __syncthreads();

    f32x4 oacc[4][2];  // [ct][qt]  O^T: rows c, cols q
    f32x4 lacc[2];     // [qt]
#pragma unroll
    for (int ct = 0; ct < 4; ++ct)
#pragma unroll
        for (int qt = 0; qt < 2; ++qt)
#pragma unroll
            for (int j = 0; j < 4; ++j) oacc[ct][qt][j] = 0.f;
#pragma unroll
    for (int qt = 0; qt < 2; ++qt)
#pragma unroll
        for (int j = 0; j < 4; ++j) lacc[qt][j] = 0.f;

    short4v onesA;
#pragma unroll
    for (int j = 0; j < 4; ++j) onesA[j] = (short)0x3F80;  // bf16 1.0

    for (int step = 0; step < 32; ++step) {
        const int cur = step & 1;

        // register prefetch of next step's K/V staging lines
        short8 rKh[2], rV[2];
        if (step < 31) {
            const int m1 = mbase + ((step + 1) << 6);
#pragma unroll
            for (int rd = 0; rd < 2; ++rd) {
                int ii = rd * 256 + t;
                int row = ii >> 3, ch = ii & 7;
                rKh[rd] = *(const short8*)&Kh_g[((m1 + row) << 6) + (ch << 3)];
                rV[rd] = *(const short8*)&Vg[(row << 12) + m1 + (ch << 3)];
            }
        }

        // ---- S^T = K x Q^T (Q hi+lo compensated, K hi only)
        f32x4 sacc[2][2];  // [mt][qt]
#pragma unroll
        for (int mt = 0; mt < 2; ++mt)
#pragma unroll
            for (int qt = 0; qt < 2; ++qt)
#pragma unroll
                for (int j = 0; j < 4; ++j) sacc[mt][qt][j] = 0.f;
#pragma unroll
        for (int ks = 0; ks < 2; ++ks)
#pragma unroll
            for (int mt = 0; mt < 2; ++mt) {
                short8 kA = ldfrag(&Khi[cur][0], mw * 32 + mt * 16 + l15,
                                   (ks << 2) + quad);
#pragma unroll
                for (int qt = 0; qt < 2; ++qt) {
                    sacc[mt][qt] = __builtin_amdgcn_mfma_f32_16x16x32_bf16(
                        kA, qHi[qt][ks], sacc[mt][qt], 0, 0, 0);
                    sacc[mt][qt] = __builtin_amdgcn_mfma_f32_16x16x32_bf16(
                        kA, qLo[qt][ks], sacc[mt][qt], 0, 0, 0);
                }
            }

        // ---- P = exp(s-30) -> bf16 B-frags IN REGISTERS (range-safe)
        short4v pB[2][2];
#pragma unroll
        for (int mt = 0; mt < 2; ++mt)
#pragma unroll
            for (int qt = 0; qt < 2; ++qt)
#pragma unroll
                for (int r = 0; r < 4; ++r)
                    pB[mt][qt][r] =
                        (short)f2bf(__expf(sacc[mt][qt][r] - 30.f));

        // ---- O^T += V^T x P^T ; l += 1 x P^T  (K=16 bf16 MFMAs)
#pragma unroll
        for (int mt = 0; mt < 2; ++mt) {
            const int mo = mw * 32 + mt * 16 + quad * 4;
#pragma unroll
            for (int ct = 0; ct < 4; ++ct) {
                short4v vA = *(const short4v*)&Vt[cur][(ct * 16 + l15) * 72 + mo];
#pragma unroll
                for (int qt = 0; qt < 2; ++qt)
                    oacc[ct][qt] = __builtin_amdgcn_mfma_f32_16x16x16bf16_1k(
                        vA, pB[mt][qt], oacc[ct][qt], 0, 0, 0);
            }
#pragma unroll
            for (int qt = 0; qt < 2; ++qt)
                lacc[qt] = __builtin_amdgcn_mfma_f32_16x16x16bf16_1k(
                    onesA, pB[mt][qt], lacc[qt], 0, 0, 0);
        }

        // ---- stage next step into cur^1
        if (step < 31) {
#pragma unroll
            for (int rd = 0; rd < 2; ++rd) {
                int ii = rd * 256 + t;
                int row = ii >> 3, ch = ii & 7;
                *(short8*)&Khi[cur ^ 1][(row << 6) + ((ch ^ (row & 7)) << 3)] =
                    rKh[rd];
                *(short8*)&Vt[cur ^ 1][row * 72 + (ch << 3)] = rV[rd];
            }
        }
        __syncthreads();  // the ONLY barrier per step
    }

    // ---- cross-wave (mw) reduce via LDS reuse, then write partials
    float* ORed = (float*)&Khi[0][0];  // 4096 floats = 16 KB
    float* lRed = (float*)&Vt[0][0];
    if (mw == 1) {
#pragma unroll
        for (int ct = 0; ct < 4; ++ct)
#pragma unroll
            for (int qt = 0; qt < 2; ++qt)
#pragma unroll
                for (int r = 0; r < 4; ++r) {
                    int e = ((ct << 1) + qt) * 4 + r;
                    ORed[qw * 2048 + e * 64 + lane] = oacc[ct][qt][r];
                }
#pragma unroll
        for (int qt = 0; qt < 2; ++qt)
            lRed[qw * 128 + qt * 64 + lane] = lacc[qt][0];
    }
    __syncthreads();
    if (mw == 0) {
#pragma unroll
        for (int ct = 0; ct < 4; ++ct)
#pragma unroll
            for (int qt = 0; qt < 2; ++qt)
#pragma unroll
                for (int r = 0; r < 4; ++r) {
                    int e = ((ct << 1) + qt) * 4 + r;
                    oacc[ct][qt][r] += ORed[qw * 2048 + e * 64 + lane];
                }
#pragma unroll
        for (int qt = 0; qt < 2; ++qt) {
            float lt = lacc[qt][0] + lRed[qw * 128 + qt * 64 + lane];
            int qg = q0 + qw * 32 + qt * 16 + l15;
            if (quad == 0) lpd[(b << 12) + qg] = lt;
#pragma unroll
            for (int ct = 0; ct < 4; ++ct) {
                float4 o4 = make_float4(oacc[ct][qt][0], oacc[ct][qt][1],
                                        oacc[ct][qt][2], oacc[ct][qt][3]);
                *(float4*)&Op[cb64 + (((size_t)qg) << 6) + ct * 16 + quad * 4] = o4;
            }
        }
    }
}
#endif  // HAVE_BF16_K16

// ---------------------------------------------------------------------------
// Fallback flash attention (r9, proven): bf16 P via swizzled LDS, K=32 PV,
// static max M=30, LDS staging + register prefetch, 2-way KV split,
// XCD swizzle, Q frags hoisted from global. 2 barriers/step, LDS 32 KB.
// ---------------------------------------------------------------------------
__global__ __launch_bounds__(256) void attn_lds_k(
    const ushort* __restrict__ thT_hi, const ushort* __restrict__ thT_lo,
    const ushort* __restrict__ phT_hi, const ushort* __restrict__ phT_lo,
    const ushort* __restrict__ g16, float* __restrict__ O0,
    float* __restrict__ O1, float* __restrict__ lp)
{
    __shared__ __align__(16) ushort Khi[4096];
    __shared__ __align__(16) ushort Vt[2][4096];
    __shared__ __align__(16) ushort Pt[4096];

    const int t = threadIdx.x;
    const int bx = blockIdx.x;
    const int xslot = bx & 7;
    const int b = xslot & 3;
    const int half = xslot >> 2;
    const int q0 = (bx >> 3) << 6;
    const int mbase = half << 11;
    const int lane = t & 63;
    const int wv = t >> 6;
    const int quad = lane >> 4;
    const int l15 = lane & 15;
    const int rhalf = (wv >> 1) << 5;
    const int chalf = (wv & 1) << 5;

    const size_t cb64 = ((size_t)b) << 18;
    const ushort* Qh_g = thT_hi + cb64 + (((size_t)q0) << 6);
    const ushort* Ql_g = thT_lo + cb64 + (((size_t)q0) << 6);
    const ushort* Kh_g = phT_hi + cb64;
    const ushort* Vg = g16 + cb64;
    float* Op = half ? O1 : O0;
    float* lpd = lp + (half << 14);
    (void)phT_lo;

    short8 aHi[2][2], aLo[2][2];
#pragma unroll
    for (int rb = 0; rb < 2; ++rb)
#pragma unroll
        for (int ks = 0; ks < 2; ++ks) {
            size_t off = (((size_t)(rhalf + (rb << 4) + l15)) << 6) +
                         ks * 32 + quad * 8;
            aHi[rb][ks] = *(const short8*)&Qh_g[off];
            aLo[rb][ks] = *(const short8*)&Ql_g[off];
        }

#pragma unroll
    for (int rd = 0; rd < 2; ++rd) {
        int ii = rd * 256 + t;
        int row = ii >> 3, ch = ii & 7;
        int off = (row << 6) + ((ch ^ (row & 7)) << 3);
        *(short8*)&Khi[off] = *(const short8*)&Kh_g[((mbase + row) << 6) + (ch << 3)];
        *(short8*)&Vt[0][off] = *(const short8*)&Vg[(row << 12) + mbase + (ch << 3)];
    }

    f32x4 oacc[2][2];
    f32x4 lacc[2];
#pragma unroll
    for (int rb = 0; rb < 2; ++rb) {
#pragma unroll
        for (int j = 0; j < 4; ++j) lacc[rb][j] = 0.f;
#pragma unroll
        for (int cb = 0; cb < 2; ++cb)
#pragma unroll
            for (int j = 0; j < 4; ++j) oacc[rb][cb][j] = 0.f;
    }
    short8 onesB;
    {
        short ov = (l15 == 0) ? (short)0x3F80 : (short)0;
#pragma unroll
        for (int j = 0; j < 8; ++j) onesB[j] = ov;
    }

    for (int step = 0; step < 32; ++step) {
        const int buf = step & 1;
        __syncthreads();

        short8 rKh[2], rV[2];
        if (step < 31) {
            const int m1 = mbase + ((step + 1) << 6);
#pragma unroll
            for (int rd = 0; rd < 2; ++rd) {
                int ii = rd * 256 + t;
                int row = ii >> 3, ch = ii & 7;
                rKh[rd] = *(const short8*)&Kh_g[((m1 + row) << 6) + (ch << 3)];
                rV[rd] = *(const short8*)&Vg[(row << 12) + m1 + (ch << 3)];
            }
        }

        short8 bHi[2][2];
#pragma unroll
        for (int cb = 0; cb < 2; ++cb) {
            int row = chalf + (cb << 4) + l15;
#pragma unroll
            for (int ks = 0; ks < 2; ++ks)
                bHi[cb][ks] = ldfrag(Khi, row, (ks << 2) + quad);
        }
        f32x4 sacc[2][2];
#pragma unroll
        for (int rb = 0; rb < 2; ++rb)
#pragma unroll
            for (int cb = 0; cb < 2; ++cb)
#pragma unroll
                for (int j = 0; j < 4; ++j) sacc[rb][cb][j] = 0.f;
#pragma unroll
        for (int ks = 0; ks < 2; ++ks)
#pragma unroll
            for (int rb = 0; rb < 2; ++rb)
#pragma unroll
                for (int cb = 0; cb < 2; ++cb) {
                    sacc[rb][cb] = __builtin_amdgcn_mfma_f32_16x16x32_bf16(
                        aHi[rb][ks], bHi[cb][ks], sacc[rb][cb], 0, 0, 0);
                    sacc[rb][cb] = __builtin_amdgcn_mfma_f32_16x16x32_bf16(
                        aLo[rb][ks], bHi[cb][ks], sacc[rb][cb], 0, 0, 0);
                }
#pragma unroll
        for (int rb = 0; rb < 2; ++rb)
#pragma unroll
            for (int cb = 0; cb < 2; ++cb) {
                int pcol = chalf + (cb << 4) + l15;
#pragma unroll
                for (int r = 0; r < 4; ++r) {
                    int prow = rhalf + (rb << 4) + (quad << 2) + r;
                    float p = __expf(sacc[rb][cb][r] - 30.f);
                    Pt[(prow << 6) + (((pcol >> 3) ^ (prow & 7)) << 3) +
                       (pcol & 7)] = f2bf(p);
                }
            }
        __syncthreads();

        short8 pa[2][2], vb[2][2];
#pragma unroll
        for (int rb = 0; rb < 2; ++rb) {
            int row = rhalf + (rb << 4) + l15;
#pragma unroll
            for (int ks = 0; ks < 2; ++ks)
                pa[rb][ks] = ldfrag(Pt, row, (ks << 2) + quad);
        }
#pragma unroll
        for (int cb = 0; cb < 2; ++cb) {
            int row = chalf + (cb << 4) + l15;
#pragma unroll
            for (int ks = 0; ks < 2; ++ks)
                vb[cb][ks] = ldfrag(&Vt[buf][0], row, (ks << 2) + quad);
        }
#pragma unroll
        for (int ks = 0; ks < 2; ++ks)
#pragma unroll
            for (int rb = 0; rb < 2; ++rb)
#pragma unroll
                for (int cb = 0; cb < 2; ++cb)
                    oacc[rb][cb] = __builtin_amdgcn_mfma_f32_16x16x32_bf16(
                        pa[rb][ks], vb[cb][ks], oacc[rb][cb], 0, 0, 0);
#pragma unroll
        for (int rb = 0; rb < 2; ++rb)
#pragma unroll
            for (int ks = 0; ks < 2; ++ks)
                lacc[rb] = __builtin_amdgcn_mfma_f32_16x16x32_bf16(
                    pa[rb][ks], onesB, lacc[rb], 0, 0, 0);

        if (step < 31) {
#pragma unroll
            for (int rd = 0; rd < 2; ++rd) {
                int ii = rd * 256 + t;
                int row = ii >> 3, ch = ii & 7;
                int off = (row << 6) + ((ch ^ (row & 7)) << 3);
                *(short8*)&Khi[off] = rKh[rd];
                *(short8*)&Vt[buf ^ 1][off] = rV[rd];
            }
        }
    }

#pragma unroll
    for (int rb = 0; rb < 2; ++rb) {
        if ((wv & 1) == 0 && l15 == 0) {
#pragma unroll
            for (int r = 0; r < 4; ++r) {
                int nn = q0 + rhalf + (rb << 4) + (quad << 2) + r;
                lpd[(b << 12) + nn] = lacc[rb][r];
            }
        }
#pragma unroll
        for (int cb = 0; cb < 2; ++cb) {
            int cc = chalf + (cb << 4) + l15;
#pragma unroll
            for (int r = 0; r < 4; ++r) {
                int nn = q0 + rhalf + (rb << 4) + (quad << 2) + r;
                Op[cb64 + (((size_t)nn) << 6) + cc] = oacc[rb][cb][r];
            }
        }
    }
}

// ---------------------------------------------------------------------------
// 1x1 conv + bias + residual, MFMA (W-hi only), with FUSED attention reduce:
// y = (O0+O1)/(l0+l1) built in-register as bf16 hi/lo A-frags.
// ---------------------------------------------------------------------------
__global__ __launch_bounds__(256) void conv1x1_k(
    const float* __restrict__ O0, const float* __restrict__ O1,
    const float* __restrict__ lp,
    const ushort* __restrict__ wh,
    const float* __restrict__ Wb, const float* __restrict__ x,
    ushort* __restrict__ zh, ushort* __restrict__ zl)
{
    const int t = threadIdx.x, lane = t & 63, wv = t >> 6;
    const int quad = lane >> 4, l15 = lane & 15;
    const int chalf = (wv & 1) << 5;
    const int P0 = blockIdx.x << 5;
    const int pbase = P0 + ((wv >> 1) << 4);
    const int b = P0 >> 12;
    const int pix = pbase + l15;   // A row
    const int nn = pix & 4095;
    const float linv = 1.f / (lp[(b << 12) + nn] + lp[16384 + (b << 12) + nn]);

    f32x4 acc[2];
#pragma unroll
    for (int j = 0; j < 4; ++j) { acc[0][j] = 0.f; acc[1][j] = 0.f; }

#pragma unroll
    for (int kc = 0; kc < 2; ++kc) {
        const int k0 = kc * 32 + quad * 8;
        size_t ao = (((size_t)pix) << 6) + k0;
        float4 a0 = *(const float4*)&O0[ao];
        float4 a1 = *(const float4*)&O0[ao + 4];
        float4 c0 = *(const float4*)&O1[ao];
        float4 c1 = *(const float4*)&O1[ao + 4];
        float v[8] = {(a0.x + c0.x) * linv, (a0.y + c0.y) * linv,
                      (a0.z + c0.z) * linv, (a0.w + c0.w) * linv,
                      (a1.x + c1.x) * linv, (a1.y + c1.y) * linv,
                      (a1.z + c1.z) * linv, (a1.w + c1.w) * linv};
        short8 aH, aL;
#pragma unroll
        for (int j = 0; j < 8; ++j) {
            ushort hh = f2bf(v[j]);
            aH[j] = (short)hh;
            aL[j] = (short)f2bf(v[j] - bf2f(hh));
        }
#pragma unroll
        for (int cb = 0; cb < 2; ++cb) {
            int co = chalf + (cb << 4) + l15;
            short8 bH = *(const short8*)&wh[(((size_t)co) << 6) + k0];
            acc[cb] = __builtin_amdgcn_mfma_f32_16x16x32_bf16(aH, bH, acc[cb], 0, 0, 0);
            acc[cb] = __builtin_amdgcn_mfma_f32_16x16x32_bf16(aL, bH, acc[cb], 0, 0, 0);
        }
    }

    const int pixb = pbase + (quad << 2);
    const int n0 = pixb & 4095;
#pragma unroll
    for (int cb = 0; cb < 2; ++cb) {
        int co = chalf + (cb << 4) + l15;
        float bias = Wb[co];
        float4 xr = *(const float4*)&x[(((size_t)(b * 64 + co)) << 12) + n0];
        float xa[4] = {xr.x, xr.y, xr.z, xr.w};
#pragma unroll
        for (int r = 0; r < 4; ++r) {
            float v = acc[cb][r] + bias + xa[r];
            size_t off = (((size_t)(pixb + r)) << 6) + co;
            ushort hh = f2bf(v);
            zh[off] = hh;
            zl[off] = f2bf(v - bf2f(hh));
        }
    }
}

// ---------------------------------------------------------------------------
// Final: BN2 apply + relu + transpose back to [B][C][H][W].
// ---------------------------------------------------------------------------
__global__ __launch_bounds__(256) void bnreluT_k(
    const float* __restrict__ c2T, const float* __restrict__ sc,
    const float* __restrict__ sh, float* __restrict__ out)
{
    __shared__ __align__(16) float T[64 * 68];
    const int b = blockIdx.x >> 6, n0 = (blockIdx.x & 63) << 6, t = threadIdx.x;
    for (int p = t; p < 1024; p += 256) {
        int n = p >> 4, c4 = (p & 15) << 2;
        float4 v = *(const float4*)&c2T[(((size_t)(b * 4096 + n0 + n)) << 6) + c4];
        float4 s4 = *(const float4*)&sc[c4];
        float4 h4 = *(const float4*)&sh[c4];
        T[(c4 + 0) * 68 + n] = fmaxf(v.x * s4.x + h4.x, 0.f);
        T[(c4 + 1) * 68 + n] = fmaxf(v.y * s4.y + h4.y, 0.f);
        T[(c4 + 2) * 68 + n] = fmaxf(v.z * s4.z + h4.z, 0.f);
        T[(c4 + 3) * 68 + n] = fmaxf(v.w * s4.w + h4.w, 0.f);
    }
    __syncthreads();
    for (int p = t; p < 1024; p += 256) {
        int c = p >> 4, n4 = (p & 15) << 2;
        float4 r;
        r.x = T[c * 68 + n4 + 0];
        r.y = T[c * 68 + n4 + 1];
        r.z = T[c * 68 + n4 + 2];
        r.w = T[c * 68 + n4 + 3];
        *(float4*)&out[(((size_t)(b * 64 + c)) << 12) + n0 + n4] = r;
    }
}

// ---------------------------------------------------------------------------
extern "C" void kernel_launch(void* const* d_in, const int* in_sizes, int n_in,
                              void* d_out, int out_size, void* d_ws,
                              size_t ws_size, hipStream_t stream)
{
    const float* x    = (const float*)d_in[0];
    const float* c1w  = (const float*)d_in[1];
    const float* bn1g = (const float*)d_in[2];
    const float* bn1b = (const float*)d_in[3];
    const float* thw  = (const float*)d_in[4];
    const float* thb  = (const float*)d_in[5];
    const float* phw  = (const float*)d_in[6];
    const float* phb  = (const float*)d_in[7];
    const float* gw   = (const float*)d_in[8];
    const float* gb   = (const float*)d_in[9];
    const float* Wwt  = (const float*)d_in[10];
    const float* Wbs  = (const float*)d_in[11];
    const float* c2w  = (const float*)d_in[12];
    const float* bn2g = (const float*)d_in[13];
    const float* bn2b = (const float*)d_in[14];
    float* out = (float*)d_out;

    float* ws = (float*)d_ws;
    // region A: xT/x1T hi+lo -> O0 fp32 -> c2T fp32
    ushort* xT_hi = (ushort*)ws;
    ushort* xT_lo = xT_hi + (1 << 20);
    ushort* x1T_hi = xT_hi;
    ushort* x1T_lo = xT_lo;
    float* O0 = ws;
    float* c2T = ws;
    // region B: c1T fp32 -> O1 fp32
    float* c1T = ws + (1 << 20);
    float* O1 = c1T;
    // region C: thT hi/lo -> zT hi/lo
    ushort* thT_hi = (ushort*)(ws + (2 << 20));
    ushort* thT_lo = thT_hi + (1 << 20);
    ushort* zT_hi = thT_hi;
    ushort* zT_lo = thT_lo;
    // regions D/E
    ushort* phT_hi = (ushort*)(ws + (3 << 20));
    ushort* phT_lo = phT_hi + (1 << 20);   // unused (phi lo dropped)
    ushort* g16 = (ushort*)(ws + (4 << 20));
    // weights / partials / stats
    ushort* wp = (ushort*)(ws + (9 << 19));
    float* part = ws + (5 << 20) - 65536;  // also lp for attention
    float* stats = ws + (5 << 20);
    float* sc1 = stats, *sh1 = stats + 64, *sc2 = stats + 128, *sh2 = stats + 192;

    ushort* wc1h = wp;
    ushort* wthh = wp + 1 * 73728;
    ushort* wphh = wp + 2 * 73728;
    ushort* wgh  = wp + 3 * 73728;
    ushort* wc2h = wp + 4 * 73728;
    ushort* w11h = wp + 5 * 73728;

    prep_all_k<<<992, 256, 0, stream>>>(x, xT_hi, xT_lo, c1w, thw, phw, gw,
                                        c2w, Wwt, wp);
    conv_mfma_k<1, 0><<<512, 256, 0, stream>>>(
        xT_hi, xT_lo, wc1h, nullptr, nullptr, nullptr, nullptr, nullptr,
        c1T, part, nullptr, nullptr, nullptr, nullptr);
    statsB_k<<<1, 256, 0, stream>>>(part, bn1g, bn1b, sc1, sh1);
    x1prep_k<<<1024, 256, 0, stream>>>(c1T, sc1, sh1, x1T_hi, x1T_lo);
    conv_mfma_k<3, 1><<<512, 256, 0, stream>>>(
        x1T_hi, x1T_lo, wthh, wphh, wgh, thb, phb, gb,
        nullptr, nullptr, thT_hi, thT_lo, phT_hi, g16);
#ifdef HAVE_BF16_K16
    attn_st_k<<<512, 256, 0, stream>>>(thT_hi, thT_lo, phT_hi, phT_lo, g16,
                                       O0, O1, part);
#else
    attn_lds_k<<<512, 256, 0, stream>>>(thT_hi, thT_lo, phT_hi, phT_lo, g16,
                                        O0, O1, part);
#endif
    conv1x1_k<<<512, 256, 0, stream>>>(O0, O1, part, w11h, Wbs, x,
                                       zT_hi, zT_lo);
    conv_mfma_k<1, 0><<<512, 256, 0, stream>>>(
        zT_hi, zT_lo, wc2h, nullptr, nullptr, nullptr, nullptr, nullptr,
        c2T, part, nullptr, nullptr, nullptr, nullptr);
    statsB_k<<<1, 256, 0, stream>>>(part, bn2g, bn2b, sc2, sh2);
    bnreluT_k<<<256, 256, 0, stream>>>(c2T, sc2, sh2, out);
}

// Round 12
// 205.905 us; speedup vs baseline: 1.3702x; 1.1532x over previous
//
#include <hip/hip_runtime.h>
#include <math.h>

// B=4, C=64, H=W=64, N=4096, NPIX=16384. All fp32 in/out.
// Pixel-major [pix][ch] bf16 hi/lo pipeline. ws (floats), footprint 5M+256:
//  A ws+0..1M   : xT hi/lo -> x1T hi/lo -> O0 (attn partial fp32) -> c2T fp32
//  B ws+1M..2M  : c1T fp32 -> O1 (attn partial fp32)
//  C ws+2M..3M  : thT hi/lo -> zT hi/lo
//  D ws+3M..4M  : phT hi (lo slot unused)
//  E ws+4M..4.5M: g16 (bf16 [B][C][N])
//  wp ws+4.5M   : FRAGMENT-PACKED weights (hi only) ; part/lp ws+5M-65536 ;
//  stats ws+5M
//
// Weight fragment layout (per 3x3 set, 36864 ushorts):
//   off = (((tap*2+kc)*4+cog)<<9) + lane*8 + j
//   where cog=co>>4, lane=((ci>>3)&3)*16 + (co&15), kc=ci>>5, j=ci&7.
//   A wave's B-frag load is then 64 lanes x 16B CONTIGUOUS (1 KB, 1 request)
//   instead of a 16-segment gather — the r8-diagnosed TA/L2 pathology.

typedef __attribute__((ext_vector_type(8))) short short8;
typedef __attribute__((ext_vector_type(4))) float f32x4;

__device__ __forceinline__ ushort f2bf(float x) {
    unsigned u = __float_as_uint(x);
    unsigned r = (u + 0x7FFFu + ((u >> 16) & 1u)) >> 16;  // RNE
    return (ushort)r;
}
__device__ __forceinline__ float bf2f(ushort h) {
    return __uint_as_float(((unsigned)h) << 16);
}

// ---------------------------------------------------------------------------
// prep_all: blocks <256: x -> xT [pix][ch] bf16 hi/lo.
// blocks 256..975: 5x 3x3 weight sets -> fragment layout (hi only).
// blocks 976..991: 1x1 weights -> fragment layout (hi only).
// ---------------------------------------------------------------------------
__global__ __launch_bounds__(256) void prep_all_k(
    const float* __restrict__ x, ushort* __restrict__ xh,
    ushort* __restrict__ xl,
    const float* __restrict__ w0, const float* __restrict__ w1,
    const float* __restrict__ w2, const float* __restrict__ w3,
    const float* __restrict__ w4, const float* __restrict__ w5,
    ushort* __restrict__ wbase)
{
    __shared__ __align__(16) float T[64 * 68];
    const int blk = blockIdx.x, t = threadIdx.x;
    if (blk < 256) {
        const int b = blk >> 6, n0 = (blk & 63) << 6;
        for (int p = t; p < 1024; p += 256) {
            int c = p >> 4, n4 = (p & 15) << 2;
            *(float4*)&T[c * 68 + n4] =
                *(const float4*)&x[(((size_t)(b * 64 + c)) << 12) + n0 + n4];
        }
        __syncthreads();
        for (int p = t; p < 1024; p += 256) {
            int n = p >> 4, c4 = (p & 15) << 2;
            size_t off = (((size_t)(b * 4096 + n0 + n)) << 6) + c4;
            ushort4 hi, lo;
            float v;
            v = T[(c4 + 0) * 68 + n]; hi.x = f2bf(v); lo.x = f2bf(v - bf2f(hi.x));
            v = T[(c4 + 1) * 68 + n]; hi.y = f2bf(v); lo.y = f2bf(v - bf2f(hi.y));
            v = T[(c4 + 2) * 68 + n]; hi.z = f2bf(v); lo.z = f2bf(v - bf2f(hi.z));
            v = T[(c4 + 3) * 68 + n]; hi.w = f2bf(v); lo.w = f2bf(v - bf2f(hi.w));
            *(ushort4*)&xh[off] = hi;
            *(ushort4*)&xl[off] = lo;
        }
    } else {
        const float* W[6] = {w0, w1, w2, w3, w4, w5};
        int q = blk - 256;
        if (q < 720) {
            int s = q / 144, bi = q - s * 144;
            int idx = bi * 256 + t;
            if (idx >= 36864) return;
            int co = idx / 576;
            int r = idx - co * 576;
            int ci = r / 9;
            int tap = r - ci * 9;
            float v = W[s][idx];
            int cog = co >> 4, lc = co & 15;
            int kc = ci >> 5, qd = (ci >> 3) & 3, j = ci & 7;
            int lane = (qd << 4) + lc;
            ushort* dst = wbase + (size_t)s * 36864;
            dst[(((((tap << 1) + kc) << 2) + cog) << 9) + (lane << 3) + j] =
                f2bf(v);
        } else {
            int idx = (q - 720) * 256 + t;
            if (idx >= 4096) return;
            float v = W[5][idx];
            int co = idx >> 6, ci = idx & 63;
            int cog = co >> 4, lc = co & 15;
            int kc = ci >> 5, qd = (ci >> 3) & 3, j = ci & 7;
            int lane = (qd << 4) + lc;
            ushort* dst = wbase + 5 * 36864;
            dst[(((kc << 2) + cog) << 9) + (lane << 3) + j] = f2bf(v);
        }
    }
}

// ---------------------------------------------------------------------------
// MFMA 3x3 conv. Block = 32 pix x 64 co, grid 512 (2 blk/CU). Wave tile
// 16pix x 32co. A hi/lo compensated for theta/mode0; phi+g use A-hi only
// (error class validated by r8's K-lo drop). Weights: fragment-packed,
// hi only, coalesced 1KB B-frag loads.
// MODE 0: fp32 out [pix][co] + fused BN partial stats -> part[bx*64+ch].
// MODE 1 (NOUT=3): theta -> hi/lo; phi -> hi; g -> bf16 [B][co][n].
// ---------------------------------------------------------------------------
template <int NOUT, int MODE>
__global__ __launch_bounds__(256) void conv_mfma_k(
    const ushort* __restrict__ Ah, const ushort* __restrict__ Al,
    const ushort* __restrict__ w0f, const ushort* __restrict__ w1f,
    const ushort* __restrict__ w2f,
    const float* __restrict__ b0, const float* __restrict__ b1,
    const float* __restrict__ b2,
    float* __restrict__ outF, float* __restrict__ part,
    ushort* __restrict__ o0h, ushort* __restrict__ o0l,
    ushort* __restrict__ o1h,
    ushort* __restrict__ o2t)
{
    __shared__ float redS[4][32], redSS[4][32];
    const int t = threadIdx.x, lane = t & 63, wv = t >> 6;
    const int quad = lane >> 4, l15 = lane & 15;
    const int bx = blockIdx.x;
    const int row = bx >> 1;                            // b*64 + h
    const int h = row & 63;
    const int wb0 = ((bx & 1) << 5) + ((wv >> 1) << 4); // wave pixel base (w)
    const int chalf = (wv & 1) << 5;

    const ushort* wf[3] = {w0f, w1f, w2f};

    f32x4 acc[NOUT][2];
#pragma unroll
    for (int o = 0; o < NOUT; ++o)
#pragma unroll
        for (int cb = 0; cb < 2; ++cb)
#pragma unroll
            for (int j = 0; j < 4; ++j) acc[o][cb][j] = 0.f;

#pragma unroll
    for (int dh = -1; dh <= 1; ++dh) {
        if ((unsigned)(h + dh) >= 64u) continue;  // block-uniform
#pragma unroll
        for (int dw = -1; dw <= 1; ++dw) {
            const int tap = (dh + 1) * 3 + (dw + 1);
#pragma unroll
            for (int kc = 0; kc < 2; ++kc) {
                const int k0 = kc * 32 + quad * 8;
                const int sw = wb0 + l15 + dw;
                short8 aH = {0, 0, 0, 0, 0, 0, 0, 0};
                short8 aL = {0, 0, 0, 0, 0, 0, 0, 0};
                if ((unsigned)sw < 64u) {
                    size_t off = (((size_t)(((row + dh) << 6) + sw)) << 6) + k0;
                    aH = *(const short8*)&Ah[off];
                    aL = *(const short8*)&Al[off];
                }
#pragma unroll
                for (int o = 0; o < NOUT; ++o)
#pragma unroll
                    for (int cb = 0; cb < 2; ++cb) {
                        int cog = ((wv & 1) << 1) + cb;
                        short8 bH = *(const short8*)
                            &wf[o][(((((tap << 1) + kc) << 2) + cog) << 9) +
                                   (lane << 3)];
                        acc[o][cb] = __builtin_amdgcn_mfma_f32_16x16x32_bf16(
                            aH, bH, acc[o][cb], 0, 0, 0);
                        if (o == 0)
                            acc[o][cb] = __builtin_amdgcn_mfma_f32_16x16x32_bf16(
                                aL, bH, acc[o][cb], 0, 0, 0);
                    }
            }
        }
    }

    if (MODE == 0) {
        float s_[2], ss_[2];
#pragma unroll
        for (int cb = 0; cb < 2; ++cb) {
            int co = chalf + (cb << 4) + l15;
            float s = 0.f, ss = 0.f;
#pragma unroll
            for (int r = 0; r < 4; ++r) {
                int pix = (row << 6) + wb0 + (quad << 2) + r;
                float v = acc[0][cb][r];
                outF[(((size_t)pix) << 6) + co] = v;
                s += v;
                ss += v * v;
            }
            s_[cb] = s;
            ss_[cb] = ss;
        }
#pragma unroll
        for (int off = 16; off < 64; off <<= 1) {
#pragma unroll
            for (int cb = 0; cb < 2; ++cb) {
                s_[cb] += __shfl_xor(s_[cb], off);
                ss_[cb] += __shfl_xor(ss_[cb], off);
            }
        }
        if (quad == 0) {
#pragma unroll
            for (int cb = 0; cb < 2; ++cb) {
                redS[wv][(cb << 4) + l15] = s_[cb];
                redSS[wv][(cb << 4) + l15] = ss_[cb];
            }
        }
        __syncthreads();
        if (t < 64) {
            int w01 = (t >> 5) & 1;  // chalf bit
            float S = redS[w01][t & 31] + redS[w01 + 2][t & 31];
            float SS = redSS[w01][t & 31] + redSS[w01 + 2][t & 31];
            part[bx * 64 + t] = S;
            part[32768 + bx * 64 + t] = SS;
        }
    } else {
        const int b = row >> 6;
#pragma unroll
        for (int cb = 0; cb < 2; ++cb) {
            int co = chalf + (cb << 4) + l15;
            float bth = b0[co], bph = b1[co], bg = b2[co];
            int pixb = (row << 6) + wb0 + (quad << 2);
#pragma unroll
            for (int r = 0; r < 4; ++r) {
                size_t off = (((size_t)(pixb + r)) << 6) + co;
                float v = acc[0][cb][r] + bth;
                ushort hh = f2bf(v);
                o0h[off] = hh;
                o0l[off] = f2bf(v - bf2f(hh));
                o1h[off] = f2bf(acc[1][cb][r] + bph);  // phi hi only
            }
            int n0 = pixb & 4095;
            ushort4 gv;
            gv.x = f2bf(acc[2][cb][0] + bg);
            gv.y = f2bf(acc[2][cb][1] + bg);
            gv.z = f2bf(acc[2][cb][2] + bg);
            gv.w = f2bf(acc[2][cb][3] + bg);
            *(ushort4*)&o2t[(((size_t)b) << 18) + (((size_t)co) << 12) + n0] = gv;
        }
    }
}

// ---------------------------------------------------------------------------
// statsB: 64 blocks (one wave per channel): reduce 512 block-partials ->
// BN scale/shift. Removes the 1-block whole-GPU serialization bubble.
// ---------------------------------------------------------------------------
__global__ __launch_bounds__(64) void statsB_k(
    const float* __restrict__ part, const float* __restrict__ gamma,
    const float* __restrict__ beta, float* __restrict__ scale,
    float* __restrict__ shift)
{
    const int c = blockIdx.x, t = threadIdx.x;
    float S = 0.f, SS = 0.f;
#pragma unroll
    for (int i = 0; i < 8; ++i) {
        int k = t + (i << 6);
        S += part[k * 64 + c];
        SS += part[32768 + k * 64 + c];
    }
#pragma unroll
    for (int off = 32; off > 0; off >>= 1) {
        S += __shfl_down(S, off);
        SS += __shfl_down(SS, off);
    }
    if (t == 0) {
        float mean = S * (1.f / 16384.f);
        float var = SS * (1.f / 16384.f) - mean * mean;
        float sc = gamma[c] * rsqrtf(var + 1e-5f);
        scale[c] = sc;
        shift[c] = beta[c] - mean * sc;
    }
}

// ---------------------------------------------------------------------------
// x1prep: c1T fp32 [pix][ch] -> relu(BN) -> x1T bf16 hi/lo.
// ---------------------------------------------------------------------------
__global__ __launch_bounds__(256) void x1prep_k(
    const float* __restrict__ c1T, const float* __restrict__ sc,
    const float* __restrict__ sh, ushort* __restrict__ xh,
    ushort* __restrict__ xl)
{
    int p = blockIdx.x * 256 + threadIdx.x;  // < 262144
    int c4 = (p & 15) << 2;
    float4 v = *(const float4*)&c1T[(size_t)p << 2];
    float4 s4 = *(const float4*)&sc[c4];
    float4 h4 = *(const float4*)&sh[c4];
    float r0 = fmaxf(v.x * s4.x + h4.x, 0.f);
    float r1 = fmaxf(v.y * s4.y + h4.y, 0.f);
    float r2 = fmaxf(v.z * s4.z + h4.z, 0.f);
    float r3 = fmaxf(v.w * s4.w + h4.w, 0.f);
    ushort4 hi, lo;
    hi.x = f2bf(r0); lo.x = f2bf(r0 - bf2f(hi.x));
    hi.y = f2bf(r1); lo.y = f2bf(r1 - bf2f(hi.y));
    hi.z = f2bf(r2); lo.z = f2bf(r2 - bf2f(hi.z));
    hi.w = f2bf(r3); lo.w = f2bf(r3 - bf2f(hi.w));
    *(ushort4*)&xh[(size_t)p << 2] = hi;
    *(ushort4*)&xl[(size_t)p << 2] = lo;
}

// ---------------------------------------------------------------------------
// Flash attention (r9/r11 proven, 51 µs): bf16 P via swizzled LDS, K=32 PV,
// static max M=30, LDS staging + register prefetch, 2-way KV split,
// XCD swizzle, Q frags hoisted from global. 2 barriers/step, LDS 32 KB.
// Outputs partial O fp32 [pix][ch] + partial l; reduce fused into conv1x1.
// ---------------------------------------------------------------------------
__device__ __forceinline__ short8 ldfrag(const ushort* base, int row, int ch) {
    return *(const short8*)&base[(row << 6) + (((ch ^ (row & 7))) << 3)];
}

__global__ __launch_bounds__(256) void attn_k(
    const ushort* __restrict__ thT_hi, const ushort* __restrict__ thT_lo,
    const ushort* __restrict__ phT_hi, const ushort* __restrict__ g16,
    float* __restrict__ O0, float* __restrict__ O1, float* __restrict__ lp)
{
    __shared__ __align__(16) ushort Khi[4096];
    __shared__ __align__(16) ushort Vt[2][4096];
    __shared__ __align__(16) ushort Pt[4096];

    const int t = threadIdx.x;
    const int bx = blockIdx.x;
    const int xslot = bx & 7;
    const int b = xslot & 3;
    const int half = xslot >> 2;
    const int q0 = (bx >> 3) << 6;
    const int mbase = half << 11;
    const int lane = t & 63;
    const int wv = t >> 6;
    const int quad = lane >> 4;
    const int l15 = lane & 15;
    const int rhalf = (wv >> 1) << 5;
    const int chalf = (wv & 1) << 5;

    const size_t cb64 = ((size_t)b) << 18;
    const ushort* Qh_g = thT_hi + cb64 + (((size_t)q0) << 6);
    const ushort* Ql_g = thT_lo + cb64 + (((size_t)q0) << 6);
    const ushort* Kh_g = phT_hi + cb64;
    const ushort* Vg = g16 + cb64;
    float* Op = half ? O1 : O0;
    float* lpd = lp + (half << 14);

    short8 aHi[2][2], aLo[2][2];
#pragma unroll
    for (int rb = 0; rb < 2; ++rb)
#pragma unroll
        for (int ks = 0; ks < 2; ++ks) {
            size_t off = (((size_t)(rhalf + (rb << 4) + l15)) << 6) +
                         ks * 32 + quad * 8;
            aHi[rb][ks] = *(const short8*)&Qh_g[off];
            aLo[rb][ks] = *(const short8*)&Ql_g[off];
        }

#pragma unroll
    for (int rd = 0; rd < 2; ++rd) {
        int ii = rd * 256 + t;
        int row = ii >> 3, ch = ii & 7;
        int off = (row << 6) + ((ch ^ (row & 7)) << 3);
        *(short8*)&Khi[off] = *(const short8*)&Kh_g[((mbase + row) << 6) + (ch << 3)];
        *(short8*)&Vt[0][off] = *(const short8*)&Vg[(row << 12) + mbase + (ch << 3)];
    }

    f32x4 oacc[2][2];
    f32x4 lacc[2];
#pragma unroll
    for (int rb = 0; rb < 2; ++rb) {
#pragma unroll
        for (int j = 0; j < 4; ++j) lacc[rb][j] = 0.f;
#pragma unroll
        for (int cb = 0; cb < 2; ++cb)
#pragma unroll
            for (int j = 0; j < 4; ++j) oacc[rb][cb][j] = 0.f;
    }
    short8 onesB;
    {
        short ov = (l15 == 0) ? (short)0x3F80 : (short)0;
#pragma unroll
        for (int j = 0; j < 8; ++j) onesB[j] = ov;
    }

    for (int step = 0; step < 32; ++step) {
        const int buf = step & 1;
        __syncthreads();

        short8 rKh[2], rV[2];
        if (step < 31) {
            const int m1 = mbase + ((step + 1) << 6);
#pragma unroll
            for (int rd = 0; rd < 2; ++rd) {
                int ii = rd * 256 + t;
                int row = ii >> 3, ch = ii & 7;
                rKh[rd] = *(const short8*)&Kh_g[((m1 + row) << 6) + (ch << 3)];
                rV[rd] = *(const short8*)&Vg[(row << 12) + m1 + (ch << 3)];
            }
        }

        short8 bHi[2][2];
#pragma unroll
        for (int cb = 0; cb < 2; ++cb) {
            int row = chalf + (cb << 4) + l15;
#pragma unroll
            for (int ks = 0; ks < 2; ++ks)
                bHi[cb][ks] = ldfrag(Khi, row, (ks << 2) + quad);
        }
        f32x4 sacc[2][2];
#pragma unroll
        for (int rb = 0; rb < 2; ++rb)
#pragma unroll
            for (int cb = 0; cb < 2; ++cb)
#pragma unroll
                for (int j = 0; j < 4; ++j) sacc[rb][cb][j] = 0.f;
#pragma unroll
        for (int ks = 0; ks < 2; ++ks)
#pragma unroll
            for (int rb = 0; rb < 2; ++rb)
#pragma unroll
                for (int cb = 0; cb < 2; ++cb) {
                    sacc[rb][cb] = __builtin_amdgcn_mfma_f32_16x16x32_bf16(
                        aHi[rb][ks], bHi[cb][ks], sacc[rb][cb], 0, 0, 0);
                    sacc[rb][cb] = __builtin_amdgcn_mfma_f32_16x16x32_bf16(
                        aLo[rb][ks], bHi[cb][ks], sacc[rb][cb], 0, 0, 0);
                }
#pragma unroll
        for (int rb = 0; rb < 2; ++rb)
#pragma unroll
            for (int cb = 0; cb < 2; ++cb) {
                int pcol = chalf + (cb << 4) + l15;
#pragma unroll
                for (int r = 0; r < 4; ++r) {
                    int prow = rhalf + (rb << 4) + (quad << 2) + r;
                    float p = __expf(sacc[rb][cb][r] - 30.f);
                    Pt[(prow << 6) + (((pcol >> 3) ^ (prow & 7)) << 3) +
                       (pcol & 7)] = f2bf(p);
                }
            }
        __syncthreads();

        short8 pa[2][2], vb[2][2];
#pragma unroll
        for (int rb = 0; rb < 2; ++rb) {
            int row = rhalf + (rb << 4) + l15;
#pragma unroll
            for (int ks = 0; ks < 2; ++ks)
                pa[rb][ks] = ldfrag(Pt, row, (ks << 2) + quad);
        }
#pragma unroll
        for (int cb = 0; cb < 2; ++cb) {
            int row = chalf + (cb << 4) + l15;
#pragma unroll
            for (int ks = 0; ks < 2; ++ks)
                vb[cb][ks] = ldfrag(&Vt[buf][0], row, (ks << 2) + quad);
        }
#pragma unroll
        for (int ks = 0; ks < 2; ++ks)
#pragma unroll
            for (int rb = 0; rb < 2; ++rb)
#pragma unroll
                for (int cb = 0; cb < 2; ++cb)
                    oacc[rb][cb] = __builtin_amdgcn_mfma_f32_16x16x32_bf16(
                        pa[rb][ks], vb[cb][ks], oacc[rb][cb], 0, 0, 0);
#pragma unroll
        for (int rb = 0; rb < 2; ++rb)
#pragma unroll
            for (int ks = 0; ks < 2; ++ks)
                lacc[rb] = __builtin_amdgcn_mfma_f32_16x16x32_bf16(
                    pa[rb][ks], onesB, lacc[rb], 0, 0, 0);

        if (step < 31) {
#pragma unroll
            for (int rd = 0; rd < 2; ++rd) {
                int ii = rd * 256 + t;
                int row = ii >> 3, ch = ii & 7;
                int off = (row << 6) + ((ch ^ (row & 7)) << 3);
                *(short8*)&Khi[off] = rKh[rd];
                *(short8*)&Vt[buf ^ 1][off] = rV[rd];
            }
        }
    }

#pragma unroll
    for (int rb = 0; rb < 2; ++rb) {
        if ((wv & 1) == 0 && l15 == 0) {
#pragma unroll
            for (int r = 0; r < 4; ++r) {
                int nn = q0 + rhalf + (rb << 4) + (quad << 2) + r;
                lpd[(b << 12) + nn] = lacc[rb][r];
            }
        }
#pragma unroll
        for (int cb = 0; cb < 2; ++cb) {
            int cc = chalf + (cb << 4) + l15;
#pragma unroll
            for (int r = 0; r < 4; ++r) {
                int nn = q0 + rhalf + (rb << 4) + (quad << 2) + r;
                Op[cb64 + (((size_t)nn) << 6) + cc] = oacc[rb][cb][r];
            }
        }
    }
}

// ---------------------------------------------------------------------------
// 1x1 conv + bias + residual, MFMA (fragment-packed W, hi only), with
// FUSED attention reduce: y = (O0+O1)/(l0+l1) in-register as bf16 hi/lo.
// ---------------------------------------------------------------------------
__global__ __launch_bounds__(256) void conv1x1_k(
    const float* __restrict__ O0, const float* __restrict__ O1,
    const float* __restrict__ lp,
    const ushort* __restrict__ wf,
    const float* __restrict__ Wb, const float* __restrict__ x,
    ushort* __restrict__ zh, ushort* __restrict__ zl)
{
    const int t = threadIdx.x, lane = t & 63, wv = t >> 6;
    const int quad = lane >> 4, l15 = lane & 15;
    const int chalf = (wv & 1) << 5;
    const int P0 = blockIdx.x << 5;
    const int pbase = P0 + ((wv >> 1) << 4);
    const int b = P0 >> 12;
    const int pix = pbase + l15;   // A row
    const int nn = pix & 4095;
    const float linv = 1.f / (lp[(b << 12) + nn] + lp[16384 + (b << 12) + nn]);

    f32x4 acc[2];
#pragma unroll
    for (int j = 0; j < 4; ++j) { acc[0][j] = 0.f; acc[1][j] = 0.f; }

#pragma unroll
    for (int kc = 0; kc < 2; ++kc) {
        const int k0 = kc * 32 + quad * 8;
        size_t ao = (((size_t)pix) << 6) + k0;
        float4 a0 = *(const float4*)&O0[ao];
        float4 a1 = *(const float4*)&O0[ao + 4];
        float4 c0 = *(const float4*)&O1[ao];
        float4 c1 = *(const float4*)&O1[ao + 4];
        float v[8] = {(a0.x + c0.x) * linv, (a0.y + c0.y) * linv,
                      (a0.z + c0.z) * linv, (a0.w + c0.w) * linv,
                      (a1.x + c1.x) * linv, (a1.y + c1.y) * linv,
                      (a1.z + c1.z) * linv, (a1.w + c1.w) * linv};
        short8 aH, aL;
#pragma unroll
        for (int j = 0; j < 8; ++j) {
            ushort hh = f2bf(v[j]);
            aH[j] = (short)hh;
            aL[j] = (short)f2bf(v[j] - bf2f(hh));
        }
#pragma unroll
        for (int cb = 0; cb < 2; ++cb) {
            int cog = ((wv & 1) << 1) + cb;
            short8 bH = *(const short8*)
                &wf[(((kc << 2) + cog) << 9) + (lane << 3)];
            acc[cb] = __builtin_amdgcn_mfma_f32_16x16x32_bf16(aH, bH, acc[cb], 0, 0, 0);
            acc[cb] = __builtin_amdgcn_mfma_f32_16x16x32_bf16(aL, bH, acc[cb], 0, 0, 0);
        }
    }

    const int pixb = pbase + (quad << 2);
    const int n0 = pixb & 4095;
#pragma unroll
    for (int cb = 0; cb < 2; ++cb) {
        int co = chalf + (cb << 4) + l15;
        float bias = Wb[co];
        float4 xr = *(const float4*)&x[(((size_t)(b * 64 + co)) << 12) + n0];
        float xa[4] = {xr.x, xr.y, xr.z, xr.w};
#pragma unroll
        for (int r = 0; r < 4; ++r) {
            float v = acc[cb][r] + bias + xa[r];
            size_t off = (((size_t)(pixb + r)) << 6) + co;
            ushort hh = f2bf(v);
            zh[off] = hh;
            zl[off] = f2bf(v - bf2f(hh));
        }
    }
}

// ---------------------------------------------------------------------------
// Final: BN2 apply + relu + transpose back to [B][C][H][W].
// ---------------------------------------------------------------------------
__global__ __launch_bounds__(256) void bnreluT_k(
    const float* __restrict__ c2T, const float* __restrict__ sc,
    const float* __restrict__ sh, float* __restrict__ out)
{
    __shared__ __align__(16) float T[64 * 68];
    const int b = blockIdx.x >> 6, n0 = (blockIdx.x & 63) << 6, t = threadIdx.x;
    for (int p = t; p < 1024; p += 256) {
        int n = p >> 4, c4 = (p & 15) << 2;
        float4 v = *(const float4*)&c2T[(((size_t)(b * 4096 + n0 + n)) << 6) + c4];
        float4 s4 = *(const float4*)&sc[c4];
        float4 h4 = *(const float4*)&sh[c4];
        T[(c4 + 0) * 68 + n] = fmaxf(v.x * s4.x + h4.x, 0.f);
        T[(c4 + 1) * 68 + n] = fmaxf(v.y * s4.y + h4.y, 0.f);
        T[(c4 + 2) * 68 + n] = fmaxf(v.z * s4.z + h4.z, 0.f);
        T[(c4 + 3) * 68 + n] = fmaxf(v.w * s4.w + h4.w, 0.f);
    }
    __syncthreads();
    for (int p = t; p < 1024; p += 256) {
        int c = p >> 4, n4 = (p & 15) << 2;
        float4 r;
        r.x = T[c * 68 + n4 + 0];
        r.y = T[c * 68 + n4 + 1];
        r.z = T[c * 68 + n4 + 2];
        r.w = T[c * 68 + n4 + 3];
        *(float4*)&out[(((size_t)(b * 64 + c)) << 12) + n0 + n4] = r;
    }
}

// ---------------------------------------------------------------------------
extern "C" void kernel_launch(void* const* d_in, const int* in_sizes, int n_in,
                              void* d_out, int out_size, void* d_ws,
                              size_t ws_size, hipStream_t stream)
{
    const float* x    = (const float*)d_in[0];
    const float* c1w  = (const float*)d_in[1];
    const float* bn1g = (const float*)d_in[2];
    const float* bn1b = (const float*)d_in[3];
    const float* thw  = (const float*)d_in[4];
    const float* thb  = (const float*)d_in[5];
    const float* phw  = (const float*)d_in[6];
    const float* phb  = (const float*)d_in[7];
    const float* gw   = (const float*)d_in[8];
    const float* gb   = (const float*)d_in[9];
    const float* Wwt  = (const float*)d_in[10];
    const float* Wbs  = (const float*)d_in[11];
    const float* c2w  = (const float*)d_in[12];
    const float* bn2g = (const float*)d_in[13];
    const float* bn2b = (const float*)d_in[14];
    float* out = (float*)d_out;

    float* ws = (float*)d_ws;
    // region A: xT/x1T hi+lo -> O0 fp32 -> c2T fp32
    ushort* xT_hi = (ushort*)ws;
    ushort* xT_lo = xT_hi + (1 << 20);
    ushort* x1T_hi = xT_hi;
    ushort* x1T_lo = xT_lo;
    float* O0 = ws;
    float* c2T = ws;
    // region B: c1T fp32 -> O1 fp32
    float* c1T = ws + (1 << 20);
    float* O1 = c1T;
    // region C: thT hi/lo -> zT hi/lo
    ushort* thT_hi = (ushort*)(ws + (2 << 20));
    ushort* thT_lo = thT_hi + (1 << 20);
    ushort* zT_hi = thT_hi;
    ushort* zT_lo = thT_lo;
    // regions D/E
    ushort* phT_hi = (ushort*)(ws + (3 << 20));
    ushort* g16 = (ushort*)(ws + (4 << 20));
    // weights (fragment-packed, hi only) / partials / stats
    ushort* wp = (ushort*)(ws + (9 << 19));
    float* part = ws + (5 << 20) - 65536;  // also lp for attention
    float* stats = ws + (5 << 20);
    float* sc1 = stats, *sh1 = stats + 64, *sc2 = stats + 128, *sh2 = stats + 192;

    ushort* wc1f = wp;
    ushort* wthf = wp + 1 * 36864;
    ushort* wphf = wp + 2 * 36864;
    ushort* wgf  = wp + 3 * 36864;
    ushort* wc2f = wp + 4 * 36864;
    ushort* w11f = wp + 5 * 36864;

    prep_all_k<<<992, 256, 0, stream>>>(x, xT_hi, xT_lo, c1w, thw, phw, gw,
                                        c2w, Wwt, wp);
    conv_mfma_k<1, 0><<<512, 256, 0, stream>>>(
        xT_hi, xT_lo, wc1f, nullptr, nullptr, nullptr, nullptr, nullptr,
        c1T, part, nullptr, nullptr, nullptr, nullptr);
    statsB_k<<<64, 64, 0, stream>>>(part, bn1g, bn1b, sc1, sh1);
    x1prep_k<<<1024, 256, 0, stream>>>(c1T, sc1, sh1, x1T_hi, x1T_lo);
    conv_mfma_k<3, 1><<<512, 256, 0, stream>>>(
        x1T_hi, x1T_lo, wthf, wphf, wgf, thb, phb, gb,
        nullptr, nullptr, thT_hi, thT_lo, phT_hi, g16);
    attn_k<<<512, 256, 0, stream>>>(thT_hi, thT_lo, phT_hi, g16, O0, O1, part);
    conv1x1_k<<<512, 256, 0, stream>>>(O0, O1, part, w11f, Wbs, x,
                                       zT_hi, zT_lo);
    conv_mfma_k<1, 0><<<512, 256, 0, stream>>>(
        zT_hi, zT_lo, wc2f, nullptr, nullptr, nullptr, nullptr, nullptr,
        c2T, part, nullptr, nullptr, nullptr, nullptr);
    statsB_k<<<64, 64, 0, stream>>>(part, bn2g, bn2b, sc2, sh2);
    bnreluT_k<<<256, 256, 0, stream>>>(c2T, sc2, sh2, out);
}

// Round 13
// 204.080 us; speedup vs baseline: 1.3825x; 1.0089x over previous
//
#include <hip/hip_runtime.h>
#include <math.h>

// B=4, C=64, H=W=64, N=4096, NPIX=16384. All fp32 in/out.
// Pixel-major [pix][ch] bf16 hi/lo pipeline. ws (floats), footprint 5M+256:
//  A ws+0..1M   : xT hi/lo -> x1T hi/lo -> O0f|O1f (attn partials, bf16-hi)
//                 -> c2T fp32
//  B ws+1M..2M  : c1T fp32 -> O2f|O3f (attn partials, bf16-hi)
//  C ws+2M..3M  : thT hi/lo -> zT hi/lo
//  D ws+3M..3.5M: phT hi
//  E ws+4M..4.5M: g16 (bf16 [B][C][N])
//  wp ws+4.5M   : FRAGMENT-PACKED weights (hi only) ; part/lp ws+5M-65536 ;
//  stats ws+5M
//
// Weight fragment layout (per 3x3 set, 36864 ushorts):
//   off = (((tap*2+kc)*4+cog)<<9) + lane*8 + j   (r12-proven: coalesced 1KB
//   B-frag loads instead of 16-segment gathers).
// Attention: 4-way KV split (grid 1024 = 4 blk/CU; r12 was 2-way/2 blk/CU
// with LDS pipe only ~57% busy — co-residency fills the barrier gaps).
// Partial O stored bf16-hi (fits 4 buffers in ws; ~0.4% y error, W(0.05)-
// attenuated + BN-normalized downstream).

typedef __attribute__((ext_vector_type(8))) short short8;
typedef __attribute__((ext_vector_type(4))) float f32x4;

__device__ __forceinline__ ushort f2bf(float x) {
    unsigned u = __float_as_uint(x);
    unsigned r = (u + 0x7FFFu + ((u >> 16) & 1u)) >> 16;  // RNE
    return (ushort)r;
}
__device__ __forceinline__ float bf2f(ushort h) {
    return __uint_as_float(((unsigned)h) << 16);
}

// ---------------------------------------------------------------------------
// prep_all: blocks <256: x -> xT [pix][ch] bf16 hi/lo.
// blocks 256..975: 5x 3x3 weight sets -> fragment layout (hi only).
// blocks 976..991: 1x1 weights -> fragment layout (hi only).
// ---------------------------------------------------------------------------
__global__ __launch_bounds__(256) void prep_all_k(
    const float* __restrict__ x, ushort* __restrict__ xh,
    ushort* __restrict__ xl,
    const float* __restrict__ w0, const float* __restrict__ w1,
    const float* __restrict__ w2, const float* __restrict__ w3,
    const float* __restrict__ w4, const float* __restrict__ w5,
    ushort* __restrict__ wbase)
{
    __shared__ __align__(16) float T[64 * 68];
    const int blk = blockIdx.x, t = threadIdx.x;
    if (blk < 256) {
        const int b = blk >> 6, n0 = (blk & 63) << 6;
        for (int p = t; p < 1024; p += 256) {
            int c = p >> 4, n4 = (p & 15) << 2;
            *(float4*)&T[c * 68 + n4] =
                *(const float4*)&x[(((size_t)(b * 64 + c)) << 12) + n0 + n4];
        }
        __syncthreads();
        for (int p = t; p < 1024; p += 256) {
            int n = p >> 4, c4 = (p & 15) << 2;
            size_t off = (((size_t)(b * 4096 + n0 + n)) << 6) + c4;
            ushort4 hi, lo;
            float v;
            v = T[(c4 + 0) * 68 + n]; hi.x = f2bf(v); lo.x = f2bf(v - bf2f(hi.x));
            v = T[(c4 + 1) * 68 + n]; hi.y = f2bf(v); lo.y = f2bf(v - bf2f(hi.y));
            v = T[(c4 + 2) * 68 + n]; hi.z = f2bf(v); lo.z = f2bf(v - bf2f(hi.z));
            v = T[(c4 + 3) * 68 + n]; hi.w = f2bf(v); lo.w = f2bf(v - bf2f(hi.w));
            *(ushort4*)&xh[off] = hi;
            *(ushort4*)&xl[off] = lo;
        }
    } else {
        const float* W[6] = {w0, w1, w2, w3, w4, w5};
        int q = blk - 256;
        if (q < 720) {
            int s = q / 144, bi = q - s * 144;
            int idx = bi * 256 + t;
            if (idx >= 36864) return;
            int co = idx / 576;
            int r = idx - co * 576;
            int ci = r / 9;
            int tap = r - ci * 9;
            float v = W[s][idx];
            int cog = co >> 4, lc = co & 15;
            int kc = ci >> 5, qd = (ci >> 3) & 3, j = ci & 7;
            int lane = (qd << 4) + lc;
            ushort* dst = wbase + (size_t)s * 36864;
            dst[(((((tap << 1) + kc) << 2) + cog) << 9) + (lane << 3) + j] =
                f2bf(v);
        } else {
            int idx = (q - 720) * 256 + t;
            if (idx >= 4096) return;
            float v = W[5][idx];
            int co = idx >> 6, ci = idx & 63;
            int cog = co >> 4, lc = co & 15;
            int kc = ci >> 5, qd = (ci >> 3) & 3, j = ci & 7;
            int lane = (qd << 4) + lc;
            ushort* dst = wbase + 5 * 36864;
            dst[(((kc << 2) + cog) << 9) + (lane << 3) + j] = f2bf(v);
        }
    }
}

// ---------------------------------------------------------------------------
// MFMA 3x3 conv. Block = 32 pix x 64 co, grid 512 (2 blk/CU). Wave tile
// 16pix x 32co. A hi/lo compensated for theta/mode0; phi+g use A-hi only.
// Weights: fragment-packed, hi only, coalesced 1KB B-frag loads.
// MODE 0: fp32 out [pix][co] + fused BN partial stats -> part[bx*64+ch].
// MODE 1 (NOUT=3): theta -> hi/lo; phi -> hi; g -> bf16 [B][co][n].
// ---------------------------------------------------------------------------
template <int NOUT, int MODE>
__global__ __launch_bounds__(256) void conv_mfma_k(
    const ushort* __restrict__ Ah, const ushort* __restrict__ Al,
    const ushort* __restrict__ w0f, const ushort* __restrict__ w1f,
    const ushort* __restrict__ w2f,
    const float* __restrict__ b0, const float* __restrict__ b1,
    const float* __restrict__ b2,
    float* __restrict__ outF, float* __restrict__ part,
    ushort* __restrict__ o0h, ushort* __restrict__ o0l,
    ushort* __restrict__ o1h,
    ushort* __restrict__ o2t)
{
    __shared__ float redS[4][32], redSS[4][32];
    const int t = threadIdx.x, lane = t & 63, wv = t >> 6;
    const int quad = lane >> 4, l15 = lane & 15;
    const int bx = blockIdx.x;
    const int row = bx >> 1;                            // b*64 + h
    const int h = row & 63;
    const int wb0 = ((bx & 1) << 5) + ((wv >> 1) << 4); // wave pixel base (w)
    const int chalf = (wv & 1) << 5;

    const ushort* wf[3] = {w0f, w1f, w2f};

    f32x4 acc[NOUT][2];
#pragma unroll
    for (int o = 0; o < NOUT; ++o)
#pragma unroll
        for (int cb = 0; cb < 2; ++cb)
#pragma unroll
            for (int j = 0; j < 4; ++j) acc[o][cb][j] = 0.f;

#pragma unroll
    for (int dh = -1; dh <= 1; ++dh) {
        if ((unsigned)(h + dh) >= 64u) continue;  // block-uniform
#pragma unroll
        for (int dw = -1; dw <= 1; ++dw) {
            const int tap = (dh + 1) * 3 + (dw + 1);
#pragma unroll
            for (int kc = 0; kc < 2; ++kc) {
                const int k0 = kc * 32 + quad * 8;
                const int sw = wb0 + l15 + dw;
                short8 aH = {0, 0, 0, 0, 0, 0, 0, 0};
                short8 aL = {0, 0, 0, 0, 0, 0, 0, 0};
                if ((unsigned)sw < 64u) {
                    size_t off = (((size_t)(((row + dh) << 6) + sw)) << 6) + k0;
                    aH = *(const short8*)&Ah[off];
                    aL = *(const short8*)&Al[off];
                }
#pragma unroll
                for (int o = 0; o < NOUT; ++o)
#pragma unroll
                    for (int cb = 0; cb < 2; ++cb) {
                        int cog = ((wv & 1) << 1) + cb;
                        short8 bH = *(const short8*)
                            &wf[o][(((((tap << 1) + kc) << 2) + cog) << 9) +
                                   (lane << 3)];
                        acc[o][cb] = __builtin_amdgcn_mfma_f32_16x16x32_bf16(
                            aH, bH, acc[o][cb], 0, 0, 0);
                        if (o == 0)
                            acc[o][cb] = __builtin_amdgcn_mfma_f32_16x16x32_bf16(
                                aL, bH, acc[o][cb], 0, 0, 0);
                    }
            }
        }
    }

    if (MODE == 0) {
        float s_[2], ss_[2];
#pragma unroll
        for (int cb = 0; cb < 2; ++cb) {
            int co = chalf + (cb << 4) + l15;
            float s = 0.f, ss = 0.f;
#pragma unroll
            for (int r = 0; r < 4; ++r) {
                int pix = (row << 6) + wb0 + (quad << 2) + r;
                float v = acc[0][cb][r];
                outF[(((size_t)pix) << 6) + co] = v;
                s += v;
                ss += v * v;
            }
            s_[cb] = s;
            ss_[cb] = ss;
        }
#pragma unroll
        for (int off = 16; off < 64; off <<= 1) {
#pragma unroll
            for (int cb = 0; cb < 2; ++cb) {
                s_[cb] += __shfl_xor(s_[cb], off);
                ss_[cb] += __shfl_xor(ss_[cb], off);
            }
        }
        if (quad == 0) {
#pragma unroll
            for (int cb = 0; cb < 2; ++cb) {
                redS[wv][(cb << 4) + l15] = s_[cb];
                redSS[wv][(cb << 4) + l15] = ss_[cb];
            }
        }
        __syncthreads();
        if (t < 64) {
            int w01 = (t >> 5) & 1;  // chalf bit
            float S = redS[w01][t & 31] + redS[w01 + 2][t & 31];
            float SS = redSS[w01][t & 31] + redSS[w01 + 2][t & 31];
            part[bx * 64 + t] = S;
            part[32768 + bx * 64 + t] = SS;
        }
    } else {
        const int b = row >> 6;
#pragma unroll
        for (int cb = 0; cb < 2; ++cb) {
            int co = chalf + (cb << 4) + l15;
            float bth = b0[co], bph = b1[co], bg = b2[co];
            int pixb = (row << 6) + wb0 + (quad << 2);
#pragma unroll
            for (int r = 0; r < 4; ++r) {
                size_t off = (((size_t)(pixb + r)) << 6) + co;
                float v = acc[0][cb][r] + bth;
                ushort hh = f2bf(v);
                o0h[off] = hh;
                o0l[off] = f2bf(v - bf2f(hh));
                o1h[off] = f2bf(acc[1][cb][r] + bph);  // phi hi only
            }
            int n0 = pixb & 4095;
            ushort4 gv;
            gv.x = f2bf(acc[2][cb][0] + bg);
            gv.y = f2bf(acc[2][cb][1] + bg);
            gv.z = f2bf(acc[2][cb][2] + bg);
            gv.w = f2bf(acc[2][cb][3] + bg);
            *(ushort4*)&o2t[(((size_t)b) << 18) + (((size_t)co) << 12) + n0] = gv;
        }
    }
}

// ---------------------------------------------------------------------------
// statsB: 64 blocks (one wave per channel): reduce 512 block-partials ->
// BN scale/shift.
// ---------------------------------------------------------------------------
__global__ __launch_bounds__(64) void statsB_k(
    const float* __restrict__ part, const float* __restrict__ gamma,
    const float* __restrict__ beta, float* __restrict__ scale,
    float* __restrict__ shift)
{
    const int c = blockIdx.x, t = threadIdx.x;
    float S = 0.f, SS = 0.f;
#pragma unroll
    for (int i = 0; i < 8; ++i) {
        int k = t + (i << 6);
        S += part[k * 64 + c];
        SS += part[32768 + k * 64 + c];
    }
#pragma unroll
    for (int off = 32; off > 0; off >>= 1) {
        S += __shfl_down(S, off);
        SS += __shfl_down(SS, off);
    }
    if (t == 0) {
        float mean = S * (1.f / 16384.f);
        float var = SS * (1.f / 16384.f) - mean * mean;
        float sc = gamma[c] * rsqrtf(var + 1e-5f);
        scale[c] = sc;
        shift[c] = beta[c] - mean * sc;
    }
}

// ---------------------------------------------------------------------------
// x1prep: c1T fp32 [pix][ch] -> relu(BN) -> x1T bf16 hi/lo.
// ---------------------------------------------------------------------------
__global__ __launch_bounds__(256) void x1prep_k(
    const float* __restrict__ c1T, const float* __restrict__ sc,
    const float* __restrict__ sh, ushort* __restrict__ xh,
    ushort* __restrict__ xl)
{
    int p = blockIdx.x * 256 + threadIdx.x;  // < 262144
    int c4 = (p & 15) << 2;
    float4 v = *(const float4*)&c1T[(size_t)p << 2];
    float4 s4 = *(const float4*)&sc[c4];
    float4 h4 = *(const float4*)&sh[c4];
    float r0 = fmaxf(v.x * s4.x + h4.x, 0.f);
    float r1 = fmaxf(v.y * s4.y + h4.y, 0.f);
    float r2 = fmaxf(v.z * s4.z + h4.z, 0.f);
    float r3 = fmaxf(v.w * s4.w + h4.w, 0.f);
    ushort4 hi, lo;
    hi.x = f2bf(r0); lo.x = f2bf(r0 - bf2f(hi.x));
    hi.y = f2bf(r1); lo.y = f2bf(r1 - bf2f(hi.y));
    hi.z = f2bf(r2); lo.z = f2bf(r2 - bf2f(hi.z));
    hi.w = f2bf(r3); lo.w = f2bf(r3 - bf2f(hi.w));
    *(ushort4*)&xh[(size_t)p << 2] = hi;
    *(ushort4*)&xl[(size_t)p << 2] = lo;
}

// ---------------------------------------------------------------------------
// Flash attention: r9/r12-proven body, 4-way KV split (grid 1024 = 4 blk/CU;
// LDS 32 KB x 4 = 128 <= 160, VGPR 92 -> 4+ waves/SIMD). XCD swizzle:
// bx&15 -> (batch, quarter); each XCD sees 1 batch x 2 quarters (~512 KB
// K/V, L2-resident). 16 steps/block. Partial O written bf16-hi.
// ---------------------------------------------------------------------------
__device__ __forceinline__ short8 ldfrag(const ushort* base, int row, int ch) {
    return *(const short8*)&base[(row << 6) + (((ch ^ (row & 7))) << 3)];
}

__global__ __launch_bounds__(256) void attn_k(
    const ushort* __restrict__ thT_hi, const ushort* __restrict__ thT_lo,
    const ushort* __restrict__ phT_hi, const ushort* __restrict__ g16,
    ushort* __restrict__ O0f, ushort* __restrict__ O1f,
    ushort* __restrict__ O2f, ushort* __restrict__ O3f,
    float* __restrict__ lp)
{
    __shared__ __align__(16) ushort Khi[4096];
    __shared__ __align__(16) ushort Vt[2][4096];
    __shared__ __align__(16) ushort Pt[4096];

    const int t = threadIdx.x;
    const int bx = blockIdx.x;
    const int xslot = bx & 15;
    const int b = xslot & 3;
    const int quarter = xslot >> 2;
    const int q0 = (bx >> 4) << 6;
    const int mbase = quarter << 10;
    const int lane = t & 63;
    const int wv = t >> 6;
    const int quad = lane >> 4;
    const int l15 = lane & 15;
    const int rhalf = (wv >> 1) << 5;
    const int chalf = (wv & 1) << 5;

    const size_t cb64 = ((size_t)b) << 18;
    const ushort* Qh_g = thT_hi + cb64 + (((size_t)q0) << 6);
    const ushort* Ql_g = thT_lo + cb64 + (((size_t)q0) << 6);
    const ushort* Kh_g = phT_hi + cb64;
    const ushort* Vg = g16 + cb64;
    ushort* Ops[4] = {O0f, O1f, O2f, O3f};
    ushort* Op = Ops[quarter];
    float* lpd = lp + (quarter << 14);

    short8 aHi[2][2], aLo[2][2];
#pragma unroll
    for (int rb = 0; rb < 2; ++rb)
#pragma unroll
        for (int ks = 0; ks < 2; ++ks) {
            size_t off = (((size_t)(rhalf + (rb << 4) + l15)) << 6) +
                         ks * 32 + quad * 8;
            aHi[rb][ks] = *(const short8*)&Qh_g[off];
            aLo[rb][ks] = *(const short8*)&Ql_g[off];
        }

#pragma unroll
    for (int rd = 0; rd < 2; ++rd) {
        int ii = rd * 256 + t;
        int row = ii >> 3, ch = ii & 7;
        int off = (row << 6) + ((ch ^ (row & 7)) << 3);
        *(short8*)&Khi[off] = *(const short8*)&Kh_g[((mbase + row) << 6) + (ch << 3)];
        *(short8*)&Vt[0][off] = *(const short8*)&Vg[(row << 12) + mbase + (ch << 3)];
    }

    f32x4 oacc[2][2];
    f32x4 lacc[2];
#pragma unroll
    for (int rb = 0; rb < 2; ++rb) {
#pragma unroll
        for (int j = 0; j < 4; ++j) lacc[rb][j] = 0.f;
#pragma unroll
        for (int cb = 0; cb < 2; ++cb)
#pragma unroll
            for (int j = 0; j < 4; ++j) oacc[rb][cb][j] = 0.f;
    }
    short8 onesB;
    {
        short ov = (l15 == 0) ? (short)0x3F80 : (short)0;
#pragma unroll
        for (int j = 0; j < 8; ++j) onesB[j] = ov;
    }

    for (int step = 0; step < 16; ++step) {
        const int buf = step & 1;
        __syncthreads();

        short8 rKh[2], rV[2];
        if (step < 15) {
            const int m1 = mbase + ((step + 1) << 6);
#pragma unroll
            for (int rd = 0; rd < 2; ++rd) {
                int ii = rd * 256 + t;
                int row = ii >> 3, ch = ii & 7;
                rKh[rd] = *(const short8*)&Kh_g[((m1 + row) << 6) + (ch << 3)];
                rV[rd] = *(const short8*)&Vg[(row << 12) + m1 + (ch << 3)];
            }
        }

        short8 bHi[2][2];
#pragma unroll
        for (int cb = 0; cb < 2; ++cb) {
            int row = chalf + (cb << 4) + l15;
#pragma unroll
            for (int ks = 0; ks < 2; ++ks)
                bHi[cb][ks] = ldfrag(Khi, row, (ks << 2) + quad);
        }
        f32x4 sacc[2][2];
#pragma unroll
        for (int rb = 0; rb < 2; ++rb)
#pragma unroll
            for (int cb = 0; cb < 2; ++cb)
#pragma unroll
                for (int j = 0; j < 4; ++j) sacc[rb][cb][j] = 0.f;
#pragma unroll
        for (int ks = 0; ks < 2; ++ks)
#pragma unroll
            for (int rb = 0; rb < 2; ++rb)
#pragma unroll
                for (int cb = 0; cb < 2; ++cb) {
                    sacc[rb][cb] = __builtin_amdgcn_mfma_f32_16x16x32_bf16(
                        aHi[rb][ks], bHi[cb][ks], sacc[rb][cb], 0, 0, 0);
                    sacc[rb][cb] = __builtin_amdgcn_mfma_f32_16x16x32_bf16(
                        aLo[rb][ks], bHi[cb][ks], sacc[rb][cb], 0, 0, 0);
                }
#pragma unroll
        for (int rb = 0; rb < 2; ++rb)
#pragma unroll
            for (int cb = 0; cb < 2; ++cb) {
                int pcol = chalf + (cb << 4) + l15;
#pragma unroll
                for (int r = 0; r < 4; ++r) {
                    int prow = rhalf + (rb << 4) + (quad << 2) + r;
                    float p = __expf(sacc[rb][cb][r] - 30.f);
                    Pt[(prow << 6) + (((pcol >> 3) ^ (prow & 7)) << 3) +
                       (pcol & 7)] = f2bf(p);
                }
            }
        __syncthreads();

        short8 pa[2][2], vb[2][2];
#pragma unroll
        for (int rb = 0; rb < 2; ++rb) {
            int row = rhalf + (rb << 4) + l15;
#pragma unroll
            for (int ks = 0; ks < 2; ++ks)
                pa[rb][ks] = ldfrag(Pt, row, (ks << 2) + quad);
        }
#pragma unroll
        for (int cb = 0; cb < 2; ++cb) {
            int row = chalf + (cb << 4) + l15;
#pragma unroll
            for (int ks = 0; ks < 2; ++ks)
                vb[cb][ks] = ldfrag(&Vt[buf][0], row, (ks << 2) + quad);
        }
#pragma unroll
        for (int ks = 0; ks < 2; ++ks)
#pragma unroll
            for (int rb = 0; rb < 2; ++rb)
#pragma unroll
                for (int cb = 0; cb < 2; ++cb)
                    oacc[rb][cb] = __builtin_amdgcn_mfma_f32_16x16x32_bf16(
                        pa[rb][ks], vb[cb][ks], oacc[rb][cb], 0, 0, 0);
#pragma unroll
        for (int rb = 0; rb < 2; ++rb)
#pragma unroll
            for (int ks = 0; ks < 2; ++ks)
                lacc[rb] = __builtin_amdgcn_mfma_f32_16x16x32_bf16(
                    pa[rb][ks], onesB, lacc[rb], 0, 0, 0);

        if (step < 15) {
#pragma unroll
            for (int rd = 0; rd < 2; ++rd) {
                int ii = rd * 256 + t;
                int row = ii >> 3, ch = ii & 7;
                int off = (row << 6) + ((ch ^ (row & 7)) << 3);
                *(short8*)&Khi[off] = rKh[rd];
                *(short8*)&Vt[buf ^ 1][off] = rV[rd];
            }
        }
    }

    // epilogue: partial l (col-0 lanes) + partial O (bf16-hi, no division)
#pragma unroll
    for (int rb = 0; rb < 2; ++rb) {
        if ((wv & 1) == 0 && l15 == 0) {
#pragma unroll
            for (int r = 0; r < 4; ++r) {
                int nn = q0 + rhalf + (rb << 4) + (quad << 2) + r;
                lpd[(b << 12) + nn] = lacc[rb][r];
            }
        }
#pragma unroll
        for (int cb = 0; cb < 2; ++cb) {
            int cc = chalf + (cb << 4) + l15;
#pragma unroll
            for (int r = 0; r < 4; ++r) {
                int nn = q0 + rhalf + (rb << 4) + (quad << 2) + r;
                Op[cb64 + (((size_t)nn) << 6) + cc] = f2bf(oacc[rb][cb][r]);
            }
        }
    }
}

// ---------------------------------------------------------------------------
// 1x1 conv + bias + residual, MFMA (fragment-packed W, hi only), with
// FUSED 4-way attention reduce: y = (ΣOq)/(Σlq), in-register bf16 hi/lo.
// ---------------------------------------------------------------------------
__global__ __launch_bounds__(256) void conv1x1_k(
    const ushort* __restrict__ O0f, const ushort* __restrict__ O1f,
    const ushort* __restrict__ O2f, const ushort* __restrict__ O3f,
    const float* __restrict__ lp,
    const ushort* __restrict__ wf,
    const float* __restrict__ Wb, const float* __restrict__ x,
    ushort* __restrict__ zh, ushort* __restrict__ zl)
{
    const int t = threadIdx.x, lane = t & 63, wv = t >> 6;
    const int quad = lane >> 4, l15 = lane & 15;
    const int chalf = (wv & 1) << 5;
    const int P0 = blockIdx.x << 5;
    const int pbase = P0 + ((wv >> 1) << 4);
    const int b = P0 >> 12;
    const int pix = pbase + l15;   // A row (global pixel)
    const float linv = 1.f / (lp[pix] + lp[16384 + pix] +
                              lp[32768 + pix] + lp[49152 + pix]);

    f32x4 acc[2];
#pragma unroll
    for (int j = 0; j < 4; ++j) { acc[0][j] = 0.f; acc[1][j] = 0.f; }

#pragma unroll
    for (int kc = 0; kc < 2; ++kc) {
        const int k0 = kc * 32 + quad * 8;
        size_t ao = (((size_t)pix) << 6) + k0;
        short8 p0 = *(const short8*)&O0f[ao];
        short8 p1 = *(const short8*)&O1f[ao];
        short8 p2 = *(const short8*)&O2f[ao];
        short8 p3 = *(const short8*)&O3f[ao];
        short8 aH, aL;
#pragma unroll
        for (int j = 0; j < 8; ++j) {
            float v = (bf2f((ushort)p0[j]) + bf2f((ushort)p1[j]) +
                       bf2f((ushort)p2[j]) + bf2f((ushort)p3[j])) * linv;
            ushort hh = f2bf(v);
            aH[j] = (short)hh;
            aL[j] = (short)f2bf(v - bf2f(hh));
        }
#pragma unroll
        for (int cb = 0; cb < 2; ++cb) {
            int cog = ((wv & 1) << 1) + cb;
            short8 bH = *(const short8*)
                &wf[(((kc << 2) + cog) << 9) + (lane << 3)];
            acc[cb] = __builtin_amdgcn_mfma_f32_16x16x32_bf16(aH, bH, acc[cb], 0, 0, 0);
            acc[cb] = __builtin_amdgcn_mfma_f32_16x16x32_bf16(aL, bH, acc[cb], 0, 0, 0);
        }
    }

    const int pixb = pbase + (quad << 2);
    const int n0 = pixb & 4095;
#pragma unroll
    for (int cb = 0; cb < 2; ++cb) {
        int co = chalf + (cb << 4) + l15;
        float bias = Wb[co];
        float4 xr = *(const float4*)&x[(((size_t)(b * 64 + co)) << 12) + n0];
        float xa[4] = {xr.x, xr.y, xr.z, xr.w};
#pragma unroll
        for (int r = 0; r < 4; ++r) {
            float v = acc[cb][r] + bias + xa[r];
            size_t off = (((size_t)(pixb + r)) << 6) + co;
            ushort hh = f2bf(v);
            zh[off] = hh;
            zl[off] = f2bf(v - bf2f(hh));
        }
    }
}

// ---------------------------------------------------------------------------
// Final: BN2 apply + relu + transpose back to [B][C][H][W].
// ---------------------------------------------------------------------------
__global__ __launch_bounds__(256) void bnreluT_k(
    const float* __restrict__ c2T, const float* __restrict__ sc,
    const float* __restrict__ sh, float* __restrict__ out)
{
    __shared__ __align__(16) float T[64 * 68];
    const int b = blockIdx.x >> 6, n0 = (blockIdx.x & 63) << 6, t = threadIdx.x;
    for (int p = t; p < 1024; p += 256) {
        int n = p >> 4, c4 = (p & 15) << 2;
        float4 v = *(const float4*)&c2T[(((size_t)(b * 4096 + n0 + n)) << 6) + c4];
        float4 s4 = *(const float4*)&sc[c4];
        float4 h4 = *(const float4*)&sh[c4];
        T[(c4 + 0) * 68 + n] = fmaxf(v.x * s4.x + h4.x, 0.f);
        T[(c4 + 1) * 68 + n] = fmaxf(v.y * s4.y + h4.y, 0.f);
        T[(c4 + 2) * 68 + n] = fmaxf(v.z * s4.z + h4.z, 0.f);
        T[(c4 + 3) * 68 + n] = fmaxf(v.w * s4.w + h4.w, 0.f);
    }
    __syncthreads();
    for (int p = t; p < 1024; p += 256) {
        int c = p >> 4, n4 = (p & 15) << 2;
        float4 r;
        r.x = T[c * 68 + n4 + 0];
        r.y = T[c * 68 + n4 + 1];
        r.z = T[c * 68 + n4 + 2];
        r.w = T[c * 68 + n4 + 3];
        *(float4*)&out[(((size_t)(b * 64 + c)) << 12) + n0 + n4] = r;
    }
}

// ---------------------------------------------------------------------------
extern "C" void kernel_launch(void* const* d_in, const int* in_sizes, int n_in,
                              void* d_out, int out_size, void* d_ws,
                              size_t ws_size, hipStream_t stream)
{
    const float* x    = (const float*)d_in[0];
    const float* c1w  = (const float*)d_in[1];
    const float* bn1g = (const float*)d_in[2];
    const float* bn1b = (const float*)d_in[3];
    const float* thw  = (const float*)d_in[4];
    const float* thb  = (const float*)d_in[5];
    const float* phw  = (const float*)d_in[6];
    const float* phb  = (const float*)d_in[7];
    const float* gw   = (const float*)d_in[8];
    const float* gb   = (const float*)d_in[9];
    const float* Wwt  = (const float*)d_in[10];
    const float* Wbs  = (const float*)d_in[11];
    const float* c2w  = (const float*)d_in[12];
    const float* bn2g = (const float*)d_in[13];
    const float* bn2b = (const float*)d_in[14];
    float* out = (float*)d_out;

    float* ws = (float*)d_ws;
    // region A: xT/x1T hi+lo -> O0f|O1f (bf16-hi partials) -> c2T fp32
    ushort* xT_hi = (ushort*)ws;
    ushort* xT_lo = xT_hi + (1 << 20);
    ushort* x1T_hi = xT_hi;
    ushort* x1T_lo = xT_lo;
    ushort* O0f = (ushort*)ws;                       // 1M ushorts
    ushort* O1f = (ushort*)(ws + (1 << 19));         // 1M ushorts
    float* c2T = ws;
    // region B: c1T fp32 -> O2f|O3f
    float* c1T = ws + (1 << 20);
    ushort* O2f = (ushort*)(ws + (1 << 20));
    ushort* O3f = (ushort*)(ws + (1 << 20) + (1 << 19));
    // region C: thT hi/lo -> zT hi/lo
    ushort* thT_hi = (ushort*)(ws + (2 << 20));
    ushort* thT_lo = thT_hi + (1 << 20);
    ushort* zT_hi = thT_hi;
    ushort* zT_lo = thT_lo;
    // regions D/E
    ushort* phT_hi = (ushort*)(ws + (3 << 20));
    ushort* g16 = (ushort*)(ws + (4 << 20));
    // weights (fragment-packed, hi only) / partials / stats
    ushort* wp = (ushort*)(ws + (9 << 19));
    float* part = ws + (5 << 20) - 65536;  // also lp (4x16384) for attention
    float* stats = ws + (5 << 20);
    float* sc1 = stats, *sh1 = stats + 64, *sc2 = stats + 128, *sh2 = stats + 192;

    ushort* wc1f = wp;
    ushort* wthf = wp + 1 * 36864;
    ushort* wphf = wp + 2 * 36864;
    ushort* wgf  = wp + 3 * 36864;
    ushort* wc2f = wp + 4 * 36864;
    ushort* w11f = wp + 5 * 36864;

    prep_all_k<<<992, 256, 0, stream>>>(x, xT_hi, xT_lo, c1w, thw, phw, gw,
                                        c2w, Wwt, wp);
    conv_mfma_k<1, 0><<<512, 256, 0, stream>>>(
        xT_hi, xT_lo, wc1f, nullptr, nullptr, nullptr, nullptr, nullptr,
        c1T, part, nullptr, nullptr, nullptr, nullptr);
    statsB_k<<<64, 64, 0, stream>>>(part, bn1g, bn1b, sc1, sh1);
    x1prep_k<<<1024, 256, 0, stream>>>(c1T, sc1, sh1, x1T_hi, x1T_lo);
    conv_mfma_k<3, 1><<<512, 256, 0, stream>>>(
        x1T_hi, x1T_lo, wthf, wphf, wgf, thb, phb, gb,
        nullptr, nullptr, thT_hi, thT_lo, phT_hi, g16);
    attn_k<<<1024, 256, 0, stream>>>(thT_hi, thT_lo, phT_hi, g16,
                                     O0f, O1f, O2f, O3f, part);
    conv1x1_k<<<512, 256, 0, stream>>>(O0f, O1f, O2f, O3f, part, w11f, Wbs, x,
                                       zT_hi, zT_lo);
    conv_mfma_k<1, 0><<<512, 256, 0, stream>>>(
        zT_hi, zT_lo, wc2f, nullptr, nullptr, nullptr, nullptr, nullptr,
        c2T, part, nullptr, nullptr, nullptr, nullptr);
    statsB_k<<<64, 64, 0, stream>>>(part, bn2g, bn2b, sc2, sh2);
    bnreluT_k<<<256, 256, 0, stream>>>(c2T, sc2, sh2, out);
}